// Round 2
// baseline (535.626 us; speedup 1.0000x reference)
//
#include <hip/hip_runtime.h>

#define NB 4
#define CIN 8
#define CO 16
#define NV 100000
#define NM 98304
#define NPOS (NM*8)          // 786432
#define NBLK ((NV+255)/256)  // 391

typedef short s16x8 __attribute__((ext_vector_type(8)));
typedef float f32x4 __attribute__((ext_vector_type(4)));
typedef unsigned short u16;
typedef unsigned int u32;

// ---- ws layout (bytes, 128-aligned) ----
#define OFF_CNT   0                      // int cnt[NV]
#define OFF_NEXT  400128                 // int next[NV]
#define OFF_STAT  800256                 // float stat[64]: sum16, sq16, scale16, shift16
#define OFF_ROWS  800640                 // int row_start[NV]
#define OFF_BSUM  1200768                // int bsum[NBLK]
#define OFF_POS   1202432                // int pos[NPOS]
#define OFF_XTB   4348160                // bf16 xtb[NV][32]  ([v][b*8+c])
#define OFF_W1B   10748160               // bf16 w1[128][64]
#define OFF_W2B   10764544               // bf16 w2[128][128]
#define OFF_H1    10797312               // bf16 h1[NV][4][16]
#define OFF_ACC   23597312               // f32 acc[4][NV][16]
#define OFF_HBUF  49197312               // bf16 hbuf[NPOS][16col][4b] (128B rows)
#define WS_NEED   149860608

static __device__ __forceinline__ u16 f2bf(float f){
  union { float f; u32 u; } v; v.f = f;
  u32 r = v.u + 0x7fffu + ((v.u >> 16) & 1u);
  return (u16)(r >> 16);
}
static __device__ __forceinline__ float bf2f(u16 h){
  union { u32 u; float f; } v; v.u = ((u32)h) << 16; return v.f;
}
static __device__ __forceinline__ u32 pk2(float a, float b){
  return (u32)f2bf(a) | (((u32)f2bf(b)) << 16);
}

// ---------- prep: int histogram + transpose x->xtb bf16 + W->bf16 ----------
__global__ __launch_bounds__(256) void k_prep(const int* __restrict__ elem,
    const float* __restrict__ x, const float* __restrict__ W1, const float* __restrict__ W2,
    int* __restrict__ cnt, u16* __restrict__ xtb, u16* __restrict__ w1b, u16* __restrict__ w2b)
{
  const int T1 = NPOS;
  const int T2 = T1 + NV*32;
  const int T3 = T2 + 128*64;
  const int T4 = T3 + 128*128;
  int stride = gridDim.x*blockDim.x;
  for (int i = blockIdx.x*blockDim.x + threadIdx.x; i < T4; i += stride){
    if (i < T1) { atomicAdd(cnt + elem[i], 1); }
    else if (i < T2){ int j = i - T1; xtb[j] = f2bf(x[(size_t)(j & 31)*NV + (j >> 5)]); }
    else if (i < T3){ int j = i - T2; w1b[j] = f2bf(W1[j]); }
    else { int j = i - T3; w2b[j] = f2bf(W2[j]); }
  }
}

// ---------- scan stage A: per-block sums ----------
__global__ __launch_bounds__(256) void k_scan_a(const int* __restrict__ cnt, int* __restrict__ bsum)
{
  int v = blockIdx.x*256 + threadIdx.x;
  int x = (v < NV) ? cnt[v] : 0;
  #pragma unroll
  for (int off = 32; off > 0; off >>= 1) x += __shfl_down(x, off);
  __shared__ int ls[4];
  int wid = threadIdx.x >> 6, lane = threadIdx.x & 63;
  if (lane == 0) ls[wid] = x;
  __syncthreads();
  if (threadIdx.x == 0) bsum[blockIdx.x] = ls[0] + ls[1] + ls[2] + ls[3];
}

// ---------- scan stage B: serial exclusive scan of block sums (tiny) ----------
__global__ void k_scan_b(int* __restrict__ bsum)
{
  if (threadIdx.x == 0){
    int s = 0;
    for (int i = 0; i < NBLK; i++){ int t = bsum[i]; bsum[i] = s; s += t; }
  }
}

// ---------- scan stage C: block-local exclusive scan + offset -> row_start ----------
__global__ __launch_bounds__(256) void k_scan_c(const int* __restrict__ cnt,
    const int* __restrict__ bsum, int* __restrict__ rows)
{
  int v = blockIdx.x*256 + threadIdx.x;
  int x = (v < NV) ? cnt[v] : 0;
  int incl = x;
  #pragma unroll
  for (int off = 1; off <= 32; off <<= 1){
    int y = __shfl_up(incl, off);
    if ((threadIdx.x & 63) >= off) incl += y;
  }
  __shared__ int wt[4];
  int wid = threadIdx.x >> 6, lane = threadIdx.x & 63;
  if (lane == 63) wt[wid] = incl;
  __syncthreads();
  int woff = 0;
  for (int w = 0; w < 4; w++) if (w < wid) woff += wt[w];
  if (v < NV) rows[v] = bsum[blockIdx.x] + woff + incl - x;
}

// ---------- pos[i] = row_start[elem[i]] + running offset ----------
__global__ __launch_bounds__(256) void k_pos(const int* __restrict__ elem,
    const int* __restrict__ rows, int* __restrict__ next, int* __restrict__ pos)
{
  int i = blockIdx.x*256 + threadIdx.x;
  if (i < NPOS){
    int v = elem[i];
    int old = atomicAdd(next + v, 1);
    pos[i] = rows[v] + old;
  }
}

// ---------- conv1: gather-GEMM, scatter rows to hbuf[pos] (no atomics) ----------
__global__ __launch_bounds__(256) void k_conv1(const int* __restrict__ elem,
    const u16* __restrict__ xtb, const u16* __restrict__ w1b,
    const float* __restrict__ b1, const int* __restrict__ pos, u16* __restrict__ hbuf)
{
  const int lane = threadIdx.x & 63;
  const int col = lane & 15, kg = lane >> 4;
  s16x8 wf[8][2];
  #pragma unroll
  for (int j2 = 0; j2 < 8; j2++)
    #pragma unroll
    for (int t = 0; t < 2; t++)
      wf[j2][t] = *(const s16x8*)(w1b + (j2*16 + col)*64 + t*32 + kg*8);

  int wave = (int)((blockIdx.x*blockDim.x + threadIdx.x) >> 6);
  int nw   = (int)((gridDim.x*blockDim.x) >> 6);
  const int ngrp = (NM*NB) >> 4;   // 24576
  for (int g = wave; g < ngrp; g += nw){
    int m_a = g*4 + ((lane & 15) >> 2);
    int b   = lane & 3;
    s16x8 af0 = *(const s16x8*)(xtb + (size_t)elem[m_a*8 + kg    ]*32 + b*8);
    s16x8 af1 = *(const s16x8*)(xtb + (size_t)elem[m_a*8 + 4 + kg]*32 + b*8);
    int m_e = g*4 + kg;
    #pragma unroll
    for (int j2 = 0; j2 < 8; j2++){
      f32x4 c = {0.f, 0.f, 0.f, 0.f};
      c = __builtin_amdgcn_mfma_f32_16x16x32_bf16(af0, wf[j2][0], c, 0, 0, 0);
      c = __builtin_amdgcn_mfma_f32_16x16x32_bf16(af1, wf[j2][1], c, 0, 0, 0);
      int pe = pos[m_e*8 + j2];
      float bb = b1[j2*16 + col];
      uint2 d; d.x = pk2(c[0]+bb, c[1]+bb); d.y = pk2(c[2]+bb, c[3]+bb);
      *(uint2*)(hbuf + (size_t)pe*64 + col*4) = d;   // 128B/row, coalesced per element
    }
  }
}

// ---------- conv2: K=128, gathers h1[v][b][16] (one 128B line per slot) ----------
__global__ __launch_bounds__(256) void k_conv2(const int* __restrict__ elem,
    const u16* __restrict__ h1, const u16* __restrict__ w2b,
    const float* __restrict__ b2, const int* __restrict__ pos, u16* __restrict__ hbuf)
{
  const int lane = threadIdx.x & 63;
  const int col = lane & 15, kg = lane >> 4;
  s16x8 wf[8][4];
  #pragma unroll
  for (int j2 = 0; j2 < 8; j2++)
    #pragma unroll
    for (int t = 0; t < 4; t++)
      wf[j2][t] = *(const s16x8*)(w2b + (j2*16 + col)*128 + t*32 + kg*8);

  int wave = (int)((blockIdx.x*blockDim.x + threadIdx.x) >> 6);
  int nw   = (int)((gridDim.x*blockDim.x) >> 6);
  const int ngrp = (NM*NB) >> 4;
  for (int g = wave; g < ngrp; g += nw){
    int m_a = g*4 + ((lane & 15) >> 2);
    int b   = lane & 3;
    s16x8 af[4];
    #pragma unroll
    for (int t = 0; t < 4; t++){
      int k0 = t*32 + kg*8;
      int j  = k0 >> 4;            // element slot
      int c0 = k0 & 15;            // channel offset
      int v  = elem[m_a*8 + j];
      af[t] = *(const s16x8*)(h1 + (size_t)v*64 + b*16 + c0);
    }
    int m_e = g*4 + kg;
    #pragma unroll
    for (int j2 = 0; j2 < 8; j2++){
      f32x4 c = {0.f, 0.f, 0.f, 0.f};
      #pragma unroll
      for (int t = 0; t < 4; t++)
        c = __builtin_amdgcn_mfma_f32_16x16x32_bf16(af[t], wf[j2][t], c, 0, 0, 0);
      int pe = pos[m_e*8 + j2];
      float bb = b2[j2*16 + col];
      uint2 d; d.x = pk2(c[0]+bb, c[1]+bb); d.y = pk2(c[2]+bb, c[3]+bb);
      *(uint2*)(hbuf + (size_t)pe*64 + col*4) = d;
    }
  }
}

// ---------- segmented reduce: hbuf rows -> acc (mean) + fused BN stats ----------
// one wave per vertex; lane = col*4 + q  (matches hbuf row layout [16col][4b])
__global__ __launch_bounds__(256) void k_reduce(const u16* __restrict__ hbuf,
    const int* __restrict__ rows, const int* __restrict__ cnt,
    float* __restrict__ acc, float* __restrict__ stat)
{
  int lane = threadIdx.x & 63, wid = threadIdx.x >> 6;
  int col = lane >> 2, q = lane & 3;
  int wv = (blockIdx.x*blockDim.x + threadIdx.x) >> 6;
  int nwv = (gridDim.x*blockDim.x) >> 6;
  float st_s = 0.f, st_q = 0.f;
  for (int v = wv; v < NV; v += nwv){
    int rs = rows[v], c = cnt[v];
    float s = 0.f;
    for (int p = rs; p < rs + c; p++)
      s += bf2f(hbuf[(size_t)p*64 + lane]);     // 128B coalesced per row
    float inv = 1.0f / fmaxf((float)c, 1.0f);
    float val = s * inv;
    acc[((size_t)q*NV + v)*16 + col] = val;
    st_s += val; st_q += val*val;
  }
  // fold the 4 batch-lanes of each col
  st_s += __shfl_xor(st_s, 1); st_s += __shfl_xor(st_s, 2);
  st_q += __shfl_xor(st_q, 1); st_q += __shfl_xor(st_q, 2);
  __shared__ float ls[4][16], lq[4][16];
  if (q == 0){ ls[wid][col] = st_s; lq[wid][col] = st_q; }
  __syncthreads();
  if (threadIdx.x < 32){
    int c2 = threadIdx.x & 15, which = threadIdx.x >> 4;
    float tot = 0.f;
    #pragma unroll
    for (int w = 0; w < 4; w++) tot += which ? lq[w][c2] : ls[w][c2];
    unsafeAtomicAdd(stat + which*16 + c2, tot);
  }
}

__global__ void k_finalize(float* __restrict__ stat, const float* __restrict__ gamma,
                           const float* __restrict__ beta)
{
  int co = threadIdx.x;
  if (co < 16){
    const float invn = 1.0f / (float)(NB*NV);
    float meanv = stat[co]*invn;
    float var   = stat[16+co]*invn - meanv*meanv;
    float sc = gamma[co]*rsqrtf(var + 1e-5f);
    stat[32+co] = sc;
    stat[48+co] = beta[co] - meanv*sc;
  }
}

// ---------- apply BN1 + relu -> h1[v][b][16] bf16 ----------
__global__ __launch_bounds__(256) void k_apply1(const float* __restrict__ acc,
    const float* __restrict__ stat, u16* __restrict__ h1)
{
  int idx = blockIdx.x*256 + threadIdx.x;
  int v = idx >> 2, b = idx & 3;
  if (v >= NV) return;
  const f32x4* a4 = (const f32x4*)(acc + ((size_t)b*NV + v)*16);
  u16 o[16] __attribute__((aligned(16)));
  #pragma unroll
  for (int k = 0; k < 4; k++){
    f32x4 vv = a4[k];
    #pragma unroll
    for (int t = 0; t < 4; t++){
      int co = k*4 + t;
      float val = vv[t]*stat[32+co] + stat[48+co];
      o[co] = f2bf(fmaxf(val, 0.f));
    }
  }
  uint4* dst = (uint4*)(h1 + (size_t)v*64 + b*16);
  dst[0] = *(uint4*)(o);
  dst[1] = *(uint4*)(o + 8);
}

// ---------- final: BN2 + skip GEMV + relu + transpose to [B][Co][N] ----------
__global__ __launch_bounds__(256) void k_final(const float* __restrict__ acc,
    const float* __restrict__ stat, const float* __restrict__ x,
    const float* __restrict__ wsk, const float* __restrict__ bsk, float* __restrict__ out)
{
  int n = blockIdx.x*blockDim.x + threadIdx.x;
  int b = blockIdx.y;
  if (n >= NV) return;
  float xv[8];
  #pragma unroll
  for (int c = 0; c < 8; c++) xv[c] = x[((size_t)b*8 + c)*NV + n];
  const f32x4* a4 = (const f32x4*)(acc + ((size_t)b*NV + n)*16);
  #pragma unroll
  for (int k = 0; k < 4; k++){
    f32x4 v = a4[k];
    #pragma unroll
    for (int t = 0; t < 4; t++){
      int co = k*4 + t;
      float val = v[t]*stat[32+co] + stat[48+co] + bsk[co];
      #pragma unroll
      for (int c = 0; c < 8; c++) val += wsk[co*8+c]*xv[c];
      out[((size_t)b*16 + co)*NV + n] = fmaxf(val, 0.f);
    }
  }
}

extern "C" void kernel_launch(void* const* d_in, const int* in_sizes, int n_in,
                              void* d_out, int out_size, void* d_ws, size_t ws_size,
                              hipStream_t stream) {
  const float* x    = (const float*)d_in[0];
  const int*   elem = (const int*)  d_in[1];
  const float* W1   = (const float*)d_in[2];
  const float* b1   = (const float*)d_in[3];
  const float* g1   = (const float*)d_in[4];
  const float* be1  = (const float*)d_in[5];
  const float* W2   = (const float*)d_in[6];
  const float* b2   = (const float*)d_in[7];
  const float* g2   = (const float*)d_in[8];
  const float* be2  = (const float*)d_in[9];
  const float* Wsk  = (const float*)d_in[10];
  const float* bsk  = (const float*)d_in[11];
  float* out = (float*)d_out;

  if (ws_size < (size_t)WS_NEED) return;  // visible failure rather than corruption

  char* ws = (char*)d_ws;
  int*   cnt  = (int*)  (ws + OFF_CNT);
  int*   next = (int*)  (ws + OFF_NEXT);
  float* stat = (float*)(ws + OFF_STAT);
  int*   rows = (int*)  (ws + OFF_ROWS);
  int*   bsum = (int*)  (ws + OFF_BSUM);
  int*   pos  = (int*)  (ws + OFF_POS);
  u16*   xtb  = (u16*)  (ws + OFF_XTB);
  u16*   w1b  = (u16*)  (ws + OFF_W1B);
  u16*   w2b  = (u16*)  (ws + OFF_W2B);
  u16*   h1   = (u16*)  (ws + OFF_H1);
  float* acc  = (float*)(ws + OFF_ACC);
  u16*   hbuf = (u16*)  (ws + OFF_HBUF);

  // zero cnt + next + stat (contiguous, ~0.8 MB)
  hipMemsetAsync(ws, 0, OFF_STAT + 384, stream);

  k_prep<<<4096, 256, 0, stream>>>(elem, x, W1, W2, cnt, xtb, w1b, w2b);
  k_scan_a<<<NBLK, 256, 0, stream>>>(cnt, bsum);
  k_scan_b<<<1, 64, 0, stream>>>(bsum);
  k_scan_c<<<NBLK, 256, 0, stream>>>(cnt, bsum, rows);
  k_pos<<<NPOS/256, 256, 0, stream>>>(elem, rows, next, pos);

  k_conv1<<<3072, 256, 0, stream>>>(elem, xtb, w1b, b1, pos, hbuf);
  k_reduce<<<512, 256, 0, stream>>>(hbuf, rows, cnt, acc, stat);
  k_finalize<<<1, 64, 0, stream>>>(stat, g1, be1);
  k_apply1<<<(NV*4 + 255)/256, 256, 0, stream>>>(acc, stat, h1);

  hipMemsetAsync(stat, 0, 128, stream);  // re-zero sum/sq only

  k_conv2<<<3072, 256, 0, stream>>>(elem, h1, w2b, b2, pos, hbuf);
  k_reduce<<<512, 256, 0, stream>>>(hbuf, rows, cnt, acc, stat);
  k_finalize<<<1, 64, 0, stream>>>(stat, g2, be2);
  k_final<<<dim3((NV+255)/256, NB), 256, 0, stream>>>(acc, stat, x, Wsk, bsk, out);
}

// Round 3
// 313.981 us; speedup vs baseline: 1.7059x; 1.7059x over previous
//
#include <hip/hip_runtime.h>

#define NB 4
#define CIN 8
#define CO 16
#define NV 100000
#define NM 98304
#define NPOS (NM*8)          // 786432
#define NBLK ((NV+255)/256)  // 391

typedef short s16x8 __attribute__((ext_vector_type(8)));
typedef float f32x4 __attribute__((ext_vector_type(4)));
typedef unsigned short u16;
typedef unsigned int u32;

// ---- ws layout (bytes, 128-aligned) ----
#define OFF_CNT   0                      // int cnt[NV]
#define OFF_NEXT  400128                 // int next[NV]
#define OFF_STAT  800256                 // float stat[64]: sum16, sq16, scale16, shift16
#define OFF_ROWS  800640                 // int row_start[NV]
#define OFF_BSUM  1200768                // int bsum[NBLK]
#define OFF_POS   1202432                // int pos[NPOS]
#define OFF_XTB   4348160                // bf16 xtb[NV][32]  ([v][b*8+c])
#define OFF_W1B   10748160               // bf16 w1[128][64]
#define OFF_W2B   10764544               // bf16 w2[128][128]
#define OFF_H1    10797312               // bf16 h1[NV][4][16]
#define OFF_ACC   23597312               // f32 acc[4][NV][16]
#define OFF_HBUF  49197312               // bf16 hbuf[NPOS][16col][4b] (128B rows)
#define WS_NEED   149860608

static __device__ __forceinline__ u16 f2bf(float f){
  union { float f; u32 u; } v; v.f = f;
  u32 r = v.u + 0x7fffu + ((v.u >> 16) & 1u);
  return (u16)(r >> 16);
}
static __device__ __forceinline__ float bf2f(u16 h){
  union { u32 u; float f; } v; v.u = ((u32)h) << 16; return v.f;
}
static __device__ __forceinline__ float bf2f_lo(u32 w){
  union { u32 u; float f; } v; v.u = w << 16; return v.f;
}
static __device__ __forceinline__ float bf2f_hi(u32 w){
  union { u32 u; float f; } v; v.u = w & 0xffff0000u; return v.f;
}
static __device__ __forceinline__ u32 pk2(float a, float b){
  return (u32)f2bf(a) | (((u32)f2bf(b)) << 16);
}

// ---------- prep: int histogram + transpose x->xtb bf16 + W->bf16 ----------
__global__ __launch_bounds__(256) void k_prep(const int* __restrict__ elem,
    const float* __restrict__ x, const float* __restrict__ W1, const float* __restrict__ W2,
    int* __restrict__ cnt, u16* __restrict__ xtb, u16* __restrict__ w1b, u16* __restrict__ w2b)
{
  const int T1 = NPOS;
  const int T2 = T1 + NV*32;
  const int T3 = T2 + 128*64;
  const int T4 = T3 + 128*128;
  int stride = gridDim.x*blockDim.x;
  for (int i = blockIdx.x*blockDim.x + threadIdx.x; i < T4; i += stride){
    if (i < T1) { atomicAdd(cnt + elem[i], 1); }
    else if (i < T2){ int j = i - T1; xtb[j] = f2bf(x[(size_t)(j & 31)*NV + (j >> 5)]); }
    else if (i < T3){ int j = i - T2; w1b[j] = f2bf(W1[j]); }
    else { int j = i - T3; w2b[j] = f2bf(W2[j]); }
  }
}

// ---------- scan stage A: per-block sums ----------
__global__ __launch_bounds__(256) void k_scan_a(const int* __restrict__ cnt, int* __restrict__ bsum)
{
  int v = blockIdx.x*256 + threadIdx.x;
  int x = (v < NV) ? cnt[v] : 0;
  #pragma unroll
  for (int off = 32; off > 0; off >>= 1) x += __shfl_down(x, off);
  __shared__ int ls[4];
  int wid = threadIdx.x >> 6, lane = threadIdx.x & 63;
  if (lane == 0) ls[wid] = x;
  __syncthreads();
  if (threadIdx.x == 0) bsum[blockIdx.x] = ls[0] + ls[1] + ls[2] + ls[3];
}

// ---------- scan stage B: wave-parallel exclusive scan of block sums ----------
__global__ void k_scan_b(int* __restrict__ bsum)
{
  int lane = threadIdx.x & 63;
  int base = 0;
  for (int i0 = 0; i0 < NBLK; i0 += 64){
    int i = i0 + lane;
    int xv = (i < NBLK) ? bsum[i] : 0;
    int incl = xv;
    #pragma unroll
    for (int off = 1; off <= 32; off <<= 1){
      int y = __shfl_up(incl, off);
      if (lane >= off) incl += y;
    }
    if (i < NBLK) bsum[i] = base + incl - xv;
    base += __shfl(incl, 63);
  }
}

// ---------- scan stage C: block-local exclusive scan + offset -> row_start ----------
__global__ __launch_bounds__(256) void k_scan_c(const int* __restrict__ cnt,
    const int* __restrict__ bsum, int* __restrict__ rows)
{
  int v = blockIdx.x*256 + threadIdx.x;
  int x = (v < NV) ? cnt[v] : 0;
  int incl = x;
  #pragma unroll
  for (int off = 1; off <= 32; off <<= 1){
    int y = __shfl_up(incl, off);
    if ((threadIdx.x & 63) >= off) incl += y;
  }
  __shared__ int wt[4];
  int wid = threadIdx.x >> 6, lane = threadIdx.x & 63;
  if (lane == 63) wt[wid] = incl;
  __syncthreads();
  int woff = 0;
  for (int w = 0; w < 4; w++) if (w < wid) woff += wt[w];
  if (v < NV) rows[v] = bsum[blockIdx.x] + woff + incl - x;
}

// ---------- pos[i] = row_start[elem[i]] + running offset ----------
__global__ __launch_bounds__(256) void k_pos(const int* __restrict__ elem,
    const int* __restrict__ rows, int* __restrict__ next, int* __restrict__ pos)
{
  int i = blockIdx.x*256 + threadIdx.x;
  if (i < NPOS){
    int v = elem[i];
    int old = atomicAdd(next + v, 1);
    pos[i] = rows[v] + old;
  }
}

// ---------- conv1: gather-GEMM, scatter rows to hbuf[pos] (no atomics) ----------
__global__ __launch_bounds__(256) void k_conv1(const int* __restrict__ elem,
    const u16* __restrict__ xtb, const u16* __restrict__ w1b,
    const float* __restrict__ b1, const int* __restrict__ pos, u16* __restrict__ hbuf)
{
  const int lane = threadIdx.x & 63;
  const int col = lane & 15, kg = lane >> 4;
  s16x8 wf[8][2];
  #pragma unroll
  for (int j2 = 0; j2 < 8; j2++)
    #pragma unroll
    for (int t = 0; t < 2; t++)
      wf[j2][t] = *(const s16x8*)(w1b + (j2*16 + col)*64 + t*32 + kg*8);

  int wave = (int)((blockIdx.x*blockDim.x + threadIdx.x) >> 6);
  int nw   = (int)((gridDim.x*blockDim.x) >> 6);
  const int ngrp = (NM*NB) >> 4;   // 24576
  for (int g = wave; g < ngrp; g += nw){
    int m_a = g*4 + ((lane & 15) >> 2);
    int b   = lane & 3;
    s16x8 af0 = *(const s16x8*)(xtb + (size_t)elem[m_a*8 + kg    ]*32 + b*8);
    s16x8 af1 = *(const s16x8*)(xtb + (size_t)elem[m_a*8 + 4 + kg]*32 + b*8);
    int m_e = g*4 + kg;
    #pragma unroll
    for (int j2 = 0; j2 < 8; j2++){
      f32x4 c = {0.f, 0.f, 0.f, 0.f};
      c = __builtin_amdgcn_mfma_f32_16x16x32_bf16(af0, wf[j2][0], c, 0, 0, 0);
      c = __builtin_amdgcn_mfma_f32_16x16x32_bf16(af1, wf[j2][1], c, 0, 0, 0);
      int pe = pos[m_e*8 + j2];
      float bb = b1[j2*16 + col];
      uint2 d; d.x = pk2(c[0]+bb, c[1]+bb); d.y = pk2(c[2]+bb, c[3]+bb);
      *(uint2*)(hbuf + (size_t)pe*64 + col*4) = d;   // 128B/row, coalesced per element
    }
  }
}

// ---------- conv2: K=128, gathers h1[v][b][16] (one 128B line per slot) ----------
__global__ __launch_bounds__(256) void k_conv2(const int* __restrict__ elem,
    const u16* __restrict__ h1, const u16* __restrict__ w2b,
    const float* __restrict__ b2, const int* __restrict__ pos, u16* __restrict__ hbuf)
{
  const int lane = threadIdx.x & 63;
  const int col = lane & 15, kg = lane >> 4;
  s16x8 wf[8][4];
  #pragma unroll
  for (int j2 = 0; j2 < 8; j2++)
    #pragma unroll
    for (int t = 0; t < 4; t++)
      wf[j2][t] = *(const s16x8*)(w2b + (j2*16 + col)*128 + t*32 + kg*8);

  int wave = (int)((blockIdx.x*blockDim.x + threadIdx.x) >> 6);
  int nw   = (int)((gridDim.x*blockDim.x) >> 6);
  const int ngrp = (NM*NB) >> 4;
  for (int g = wave; g < ngrp; g += nw){
    int m_a = g*4 + ((lane & 15) >> 2);
    int b   = lane & 3;
    s16x8 af[4];
    #pragma unroll
    for (int t = 0; t < 4; t++){
      int k0 = t*32 + kg*8;
      int j  = k0 >> 4;            // element slot
      int c0 = k0 & 15;            // channel offset
      int v  = elem[m_a*8 + j];
      af[t] = *(const s16x8*)(h1 + (size_t)v*64 + b*16 + c0);
    }
    int m_e = g*4 + kg;
    #pragma unroll
    for (int j2 = 0; j2 < 8; j2++){
      f32x4 c = {0.f, 0.f, 0.f, 0.f};
      #pragma unroll
      for (int t = 0; t < 4; t++)
        c = __builtin_amdgcn_mfma_f32_16x16x32_bf16(af[t], wf[j2][t], c, 0, 0, 0);
      int pe = pos[m_e*8 + j2];
      float bb = b2[j2*16 + col];
      uint2 d; d.x = pk2(c[0]+bb, c[1]+bb); d.y = pk2(c[2]+bb, c[3]+bb);
      *(uint2*)(hbuf + (size_t)pe*64 + col*4) = d;
    }
  }
}

// ---------- segmented reduce: hbuf rows -> acc (mean) + fused BN stats ----------
// one wave per vertex (grid-stride); lane covers (col = lane&15, row-group g = lane>>4)
// each lane loads uint2 = 4 batch values of its col for row p+g -> wave eats 4 rows/instr
__global__ __launch_bounds__(256) void k_reduce(const u16* __restrict__ hbuf,
    const int* __restrict__ rows, const int* __restrict__ cnt,
    float* __restrict__ acc, float* __restrict__ stat)
{
  int lane = threadIdx.x & 63, wid = threadIdx.x >> 6;
  int col = lane & 15, g = lane >> 4;
  int wv = (blockIdx.x*blockDim.x + threadIdx.x) >> 6;
  int nwv = (gridDim.x*blockDim.x) >> 6;
  float st_s = 0.f, st_q = 0.f;
  for (int v = wv; v < NV; v += nwv){
    int rs = rows[v], c = cnt[v];
    const u16* base = hbuf + (size_t)rs*64 + col*4;
    float s0 = 0.f, s1 = 0.f, s2 = 0.f, s3 = 0.f;
    for (int p4 = 0; p4 < c; p4 += 8){
      int pa = p4 + g, pb = p4 + 4 + g;
      uint2 da = {0u,0u}, db = {0u,0u};
      if (pa < c) da = *(const uint2*)(base + (size_t)pa*64);
      if (pb < c) db = *(const uint2*)(base + (size_t)pb*64);
      s0 += bf2f_lo(da.x) + bf2f_lo(db.x);
      s1 += bf2f_hi(da.x) + bf2f_hi(db.x);
      s2 += bf2f_lo(da.y) + bf2f_lo(db.y);
      s3 += bf2f_hi(da.y) + bf2f_hi(db.y);
    }
    // fold the 4 row-groups (lanes col, col+16, col+32, col+48)
    s0 += __shfl_xor(s0, 16); s0 += __shfl_xor(s0, 32);
    s1 += __shfl_xor(s1, 16); s1 += __shfl_xor(s1, 32);
    s2 += __shfl_xor(s2, 16); s2 += __shfl_xor(s2, 32);
    s3 += __shfl_xor(s3, 16); s3 += __shfl_xor(s3, 32);
    float inv = 1.0f / fmaxf((float)c, 1.0f);
    float val = (g == 0 ? s0 : g == 1 ? s1 : g == 2 ? s2 : s3) * inv;
    acc[((size_t)g*NV + v)*16 + col] = val;   // lane writes its (q=g, col)
    st_s += val; st_q += val*val;
  }
  // fold stats over q (same col in lanes col+16g)
  st_s += __shfl_xor(st_s, 16); st_s += __shfl_xor(st_s, 32);
  st_q += __shfl_xor(st_q, 16); st_q += __shfl_xor(st_q, 32);
  __shared__ float ls[4][16], lq[4][16];
  if (lane < 16){ ls[wid][lane] = st_s; lq[wid][lane] = st_q; }
  __syncthreads();
  if (threadIdx.x < 32){
    int c2 = threadIdx.x & 15, which = threadIdx.x >> 4;
    float tot = 0.f;
    #pragma unroll
    for (int w = 0; w < 4; w++) tot += which ? lq[w][c2] : ls[w][c2];
    unsafeAtomicAdd(stat + which*16 + c2, tot);
  }
}

__global__ void k_finalize(float* __restrict__ stat, const float* __restrict__ gamma,
                           const float* __restrict__ beta)
{
  int co = threadIdx.x;
  if (co < 16){
    const float invn = 1.0f / (float)(NB*NV);
    float meanv = stat[co]*invn;
    float var   = stat[16+co]*invn - meanv*meanv;
    float sc = gamma[co]*rsqrtf(var + 1e-5f);
    stat[32+co] = sc;
    stat[48+co] = beta[co] - meanv*sc;
  }
}

// ---------- apply BN1 + relu -> h1[v][b][16] bf16 ----------
__global__ __launch_bounds__(256) void k_apply1(const float* __restrict__ acc,
    const float* __restrict__ stat, u16* __restrict__ h1)
{
  int idx = blockIdx.x*256 + threadIdx.x;
  int v = idx >> 2, b = idx & 3;
  if (v >= NV) return;
  const f32x4* a4 = (const f32x4*)(acc + ((size_t)b*NV + v)*16);
  u16 o[16] __attribute__((aligned(16)));
  #pragma unroll
  for (int k = 0; k < 4; k++){
    f32x4 vv = a4[k];
    #pragma unroll
    for (int t = 0; t < 4; t++){
      int co = k*4 + t;
      float val = vv[t]*stat[32+co] + stat[48+co];
      o[co] = f2bf(fmaxf(val, 0.f));
    }
  }
  uint4* dst = (uint4*)(h1 + (size_t)v*64 + b*16);
  dst[0] = *(uint4*)(o);
  dst[1] = *(uint4*)(o + 8);
}

// ---------- final: BN2 + skip GEMV + relu + transpose to [B][Co][N] ----------
__global__ __launch_bounds__(256) void k_final(const float* __restrict__ acc,
    const float* __restrict__ stat, const float* __restrict__ x,
    const float* __restrict__ wsk, const float* __restrict__ bsk, float* __restrict__ out)
{
  int n = blockIdx.x*blockDim.x + threadIdx.x;
  int b = blockIdx.y;
  if (n >= NV) return;
  float xv[8];
  #pragma unroll
  for (int c = 0; c < 8; c++) xv[c] = x[((size_t)b*8 + c)*NV + n];
  const f32x4* a4 = (const f32x4*)(acc + ((size_t)b*NV + n)*16);
  #pragma unroll
  for (int k = 0; k < 4; k++){
    f32x4 v = a4[k];
    #pragma unroll
    for (int t = 0; t < 4; t++){
      int co = k*4 + t;
      float val = v[t]*stat[32+co] + stat[48+co] + bsk[co];
      #pragma unroll
      for (int c = 0; c < 8; c++) val += wsk[co*8+c]*xv[c];
      out[((size_t)b*16 + co)*NV + n] = fmaxf(val, 0.f);
    }
  }
}

extern "C" void kernel_launch(void* const* d_in, const int* in_sizes, int n_in,
                              void* d_out, int out_size, void* d_ws, size_t ws_size,
                              hipStream_t stream) {
  const float* x    = (const float*)d_in[0];
  const int*   elem = (const int*)  d_in[1];
  const float* W1   = (const float*)d_in[2];
  const float* b1   = (const float*)d_in[3];
  const float* g1   = (const float*)d_in[4];
  const float* be1  = (const float*)d_in[5];
  const float* W2   = (const float*)d_in[6];
  const float* b2   = (const float*)d_in[7];
  const float* g2   = (const float*)d_in[8];
  const float* be2  = (const float*)d_in[9];
  const float* Wsk  = (const float*)d_in[10];
  const float* bsk  = (const float*)d_in[11];
  float* out = (float*)d_out;

  if (ws_size < (size_t)WS_NEED) return;  // visible failure rather than corruption

  char* ws = (char*)d_ws;
  int*   cnt  = (int*)  (ws + OFF_CNT);
  int*   next = (int*)  (ws + OFF_NEXT);
  float* stat = (float*)(ws + OFF_STAT);
  int*   rows = (int*)  (ws + OFF_ROWS);
  int*   bsum = (int*)  (ws + OFF_BSUM);
  int*   pos  = (int*)  (ws + OFF_POS);
  u16*   xtb  = (u16*)  (ws + OFF_XTB);
  u16*   w1b  = (u16*)  (ws + OFF_W1B);
  u16*   w2b  = (u16*)  (ws + OFF_W2B);
  u16*   h1   = (u16*)  (ws + OFF_H1);
  float* acc  = (float*)(ws + OFF_ACC);
  u16*   hbuf = (u16*)  (ws + OFF_HBUF);

  // zero cnt + next + stat (contiguous, ~0.8 MB)
  hipMemsetAsync(ws, 0, OFF_STAT + 384, stream);

  k_prep<<<4096, 256, 0, stream>>>(elem, x, W1, W2, cnt, xtb, w1b, w2b);
  k_scan_a<<<NBLK, 256, 0, stream>>>(cnt, bsum);
  k_scan_b<<<1, 64, 0, stream>>>(bsum);
  k_scan_c<<<NBLK, 256, 0, stream>>>(cnt, bsum, rows);
  k_pos<<<NPOS/256, 256, 0, stream>>>(elem, rows, next, pos);

  k_conv1<<<3072, 256, 0, stream>>>(elem, xtb, w1b, b1, pos, hbuf);
  k_reduce<<<2048, 256, 0, stream>>>(hbuf, rows, cnt, acc, stat);
  k_finalize<<<1, 64, 0, stream>>>(stat, g1, be1);
  k_apply1<<<(NV*4 + 255)/256, 256, 0, stream>>>(acc, stat, h1);

  hipMemsetAsync(stat, 0, 128, stream);  // re-zero sum/sq only

  k_conv2<<<3072, 256, 0, stream>>>(elem, h1, w2b, b2, pos, hbuf);
  k_reduce<<<2048, 256, 0, stream>>>(hbuf, rows, cnt, acc, stat);
  k_finalize<<<1, 64, 0, stream>>>(stat, g2, be2);
  k_final<<<dim3((NV+255)/256, NB), 256, 0, stream>>>(acc, stat, x, Wsk, bsk, out);
}

// Round 4
// 278.066 us; speedup vs baseline: 1.9263x; 1.1292x over previous
//
#include <hip/hip_runtime.h>

#define NB 4
#define CIN 8
#define CO 16
#define NV 100000
#define NM 98304
#define NPOS (NM*8)          // 786432
#define NBLK ((NV+255)/256)  // 391

typedef short s16x8 __attribute__((ext_vector_type(8)));
typedef float f32x4 __attribute__((ext_vector_type(4)));
typedef unsigned short u16;
typedef unsigned int u32;

// ---- ws layout (bytes, 128-aligned) ---- (unchanged from round 2)
#define OFF_CNT   0                      // int cnt[NV]
#define OFF_NEXT  400128                 // int next[NV]
#define OFF_STAT  800256                 // float stat[64]
#define OFF_ROWS  800640                 // int row_start[NV]
#define OFF_BSUM  1200768                // int bsum[NBLK]
#define OFF_POS   1202432                // int pos[NPOS]
#define OFF_XTB   4348160                // bf16 xtb[NV][32]  ([v][b*8+c])
#define OFF_W1B   10748160               // bf16 w1[128][64]
#define OFF_W2B   10764544               // bf16 w2[128][128]
#define OFF_H1    10797312               // bf16 h1[NV][4][16]
#define OFF_ACC   23597312               // f32 acc[4][NV][16]
#define OFF_HBUF  49197312               // bf16 hbuf[NPOS][16col][4b] (128B rows)
#define WS_NEED   149860608

static __device__ __forceinline__ u16 f2bf(float f){
  union { float f; u32 u; } v; v.f = f;
  u32 r = v.u + 0x7fffu + ((v.u >> 16) & 1u);
  return (u16)(r >> 16);
}
static __device__ __forceinline__ float bf2f_lo(u32 w){
  union { u32 u; float f; } v; v.u = w << 16; return v.f;
}
static __device__ __forceinline__ float bf2f_hi(u32 w){
  union { u32 u; float f; } v; v.u = w & 0xffff0000u; return v.f;
}
static __device__ __forceinline__ u32 pk2(float a, float b){
  return (u32)f2bf(a) | (((u32)f2bf(b)) << 16);
}

// ---------- hist: element histogram + W->bf16 ----------
__global__ __launch_bounds__(256) void k_hist(const int* __restrict__ elem,
    const float* __restrict__ W1, const float* __restrict__ W2,
    int* __restrict__ cnt, u16* __restrict__ w1b, u16* __restrict__ w2b)
{
  const int T1 = NPOS;
  const int T2 = T1 + 128*64;
  const int T3 = T2 + 128*128;
  int stride = gridDim.x*blockDim.x;
  for (int i = blockIdx.x*blockDim.x + threadIdx.x; i < T3; i += stride){
    if (i < T1) { atomicAdd(cnt + elem[i], 1); }
    else if (i < T2){ int j = i - T1; w1b[j] = f2bf(W1[j]); }
    else { int j = i - T2; w2b[j] = f2bf(W2[j]); }
  }
}

// ---------- transpose x[32][NV] -> xtb[v][32] bf16 via LDS tile ----------
__global__ __launch_bounds__(256) void k_xt(const float* __restrict__ x, u16* __restrict__ xtb)
{
  __shared__ float tile[32][257];
  int t = threadIdx.x;
  int v0 = blockIdx.x*256;
  #pragma unroll
  for (int r = 0; r < 32; r++){
    int v = v0 + t;
    tile[r][t] = (v < NV) ? x[(size_t)r*NV + v] : 0.f;
  }
  __syncthreads();
  int v = v0 + t;
  if (v < NV){
    u16 o[32] __attribute__((aligned(16)));
    #pragma unroll
    for (int r = 0; r < 32; r++) o[r] = f2bf(tile[r][t]);
    uint4* dst = (uint4*)(xtb + (size_t)v*32);
    #pragma unroll
    for (int k = 0; k < 4; k++) dst[k] = *(uint4*)(o + k*8);
  }
}

// ---------- scan stage A: per-block sums ----------
__global__ __launch_bounds__(256) void k_scan_a(const int* __restrict__ cnt, int* __restrict__ bsum)
{
  int v = blockIdx.x*256 + threadIdx.x;
  int x = (v < NV) ? cnt[v] : 0;
  #pragma unroll
  for (int off = 32; off > 0; off >>= 1) x += __shfl_down(x, off);
  __shared__ int ls[4];
  int wid = threadIdx.x >> 6, lane = threadIdx.x & 63;
  if (lane == 0) ls[wid] = x;
  __syncthreads();
  if (threadIdx.x == 0) bsum[blockIdx.x] = ls[0] + ls[1] + ls[2] + ls[3];
}

// ---------- scan stage B: wave-parallel exclusive scan of block sums ----------
__global__ void k_scan_b(int* __restrict__ bsum)
{
  int lane = threadIdx.x & 63;
  int base = 0;
  for (int i0 = 0; i0 < NBLK; i0 += 64){
    int i = i0 + lane;
    int xv = (i < NBLK) ? bsum[i] : 0;
    int incl = xv;
    #pragma unroll
    for (int off = 1; off <= 32; off <<= 1){
      int y = __shfl_up(incl, off);
      if (lane >= off) incl += y;
    }
    if (i < NBLK) bsum[i] = base + incl - xv;
    base += __shfl(incl, 63);
  }
}

// ---------- scan stage C: block-local exclusive scan + offset -> row_start ----------
__global__ __launch_bounds__(256) void k_scan_c(const int* __restrict__ cnt,
    const int* __restrict__ bsum, int* __restrict__ rows)
{
  int v = blockIdx.x*256 + threadIdx.x;
  int x = (v < NV) ? cnt[v] : 0;
  int incl = x;
  #pragma unroll
  for (int off = 1; off <= 32; off <<= 1){
    int y = __shfl_up(incl, off);
    if ((threadIdx.x & 63) >= off) incl += y;
  }
  __shared__ int wt[4];
  int wid = threadIdx.x >> 6, lane = threadIdx.x & 63;
  if (lane == 63) wt[wid] = incl;
  __syncthreads();
  int woff = 0;
  for (int w = 0; w < 4; w++) if (w < wid) woff += wt[w];
  if (v < NV) rows[v] = bsum[blockIdx.x] + woff + incl - x;
}

// ---------- pos[i] = row_start[elem[i]] + running offset ----------
__global__ __launch_bounds__(256) void k_pos(const int* __restrict__ elem,
    const int* __restrict__ rows, int* __restrict__ next, int* __restrict__ pos)
{
  int i = blockIdx.x*256 + threadIdx.x;
  if (i < NPOS){
    int v = elem[i];
    int old = atomicAdd(next + v, 1);
    pos[i] = rows[v] + old;
  }
}

// ---------- conv1: one-shot, 2 groups/wave straight-line, W1 in regs ----------
// grid MUST be 3072 blocks x 256 (12288 waves; ngrp = 24576)
__global__ __launch_bounds__(256) void k_conv1(const int* __restrict__ elem,
    const u16* __restrict__ xtb, const u16* __restrict__ w1b,
    const float* __restrict__ b1, const int* __restrict__ pos, u16* __restrict__ hbuf)
{
  const int lane = threadIdx.x & 63;
  const int col = lane & 15, kg = lane >> 4, b = lane & 3;
  s16x8 wf[8][2];
  #pragma unroll
  for (int j2 = 0; j2 < 8; j2++)
    #pragma unroll
    for (int t = 0; t < 2; t++)
      wf[j2][t] = *(const s16x8*)(w1b + (j2*16 + col)*64 + t*32 + kg*8);
  float bb[8];
  #pragma unroll
  for (int j2 = 0; j2 < 8; j2++) bb[j2] = b1[j2*16 + col];

  int wave = (int)((blockIdx.x*blockDim.x + threadIdx.x) >> 6);
  int g0 = wave, g1 = wave + 12288;
  int ma0 = g0*4 + (col >> 2), ma1 = g1*4 + (col >> 2);
  int me0 = g0*4 + kg,         me1 = g1*4 + kg;

  // issue all loads up front (two independent chains)
  int e00 = elem[ma0*8 + kg], e01 = elem[ma0*8 + 4 + kg];
  int e10 = elem[ma1*8 + kg], e11 = elem[ma1*8 + 4 + kg];
  int4 p0l = *(const int4*)(pos + me0*8), p0h = *(const int4*)(pos + me0*8 + 4);
  int4 p1l = *(const int4*)(pos + me1*8), p1h = *(const int4*)(pos + me1*8 + 4);
  s16x8 a00 = *(const s16x8*)(xtb + (size_t)e00*32 + b*8);
  s16x8 a01 = *(const s16x8*)(xtb + (size_t)e01*32 + b*8);
  s16x8 a10 = *(const s16x8*)(xtb + (size_t)e10*32 + b*8);
  s16x8 a11 = *(const s16x8*)(xtb + (size_t)e11*32 + b*8);

  int pe0[8] = {p0l.x,p0l.y,p0l.z,p0l.w,p0h.x,p0h.y,p0h.z,p0h.w};
  int pe1[8] = {p1l.x,p1l.y,p1l.z,p1l.w,p1h.x,p1h.y,p1h.z,p1h.w};

  #pragma unroll
  for (int j2 = 0; j2 < 8; j2++){
    f32x4 c = {0.f,0.f,0.f,0.f};
    c = __builtin_amdgcn_mfma_f32_16x16x32_bf16(a00, wf[j2][0], c, 0, 0, 0);
    c = __builtin_amdgcn_mfma_f32_16x16x32_bf16(a01, wf[j2][1], c, 0, 0, 0);
    uint2 d; d.x = pk2(c[0]+bb[j2], c[1]+bb[j2]); d.y = pk2(c[2]+bb[j2], c[3]+bb[j2]);
    *(uint2*)(hbuf + (size_t)pe0[j2]*64 + col*4) = d;
  }
  #pragma unroll
  for (int j2 = 0; j2 < 8; j2++){
    f32x4 c = {0.f,0.f,0.f,0.f};
    c = __builtin_amdgcn_mfma_f32_16x16x32_bf16(a10, wf[j2][0], c, 0, 0, 0);
    c = __builtin_amdgcn_mfma_f32_16x16x32_bf16(a11, wf[j2][1], c, 0, 0, 0);
    uint2 d; d.x = pk2(c[0]+bb[j2], c[1]+bb[j2]); d.y = pk2(c[2]+bb[j2], c[3]+bb[j2]);
    *(uint2*)(hbuf + (size_t)pe1[j2]*64 + col*4) = d;
  }
}

// ---------- conv2: one-shot, 2 groups/wave, W2 staged in LDS (frag order) ----------
// grid MUST be 3072 blocks x 256
__global__ __launch_bounds__(256) void k_conv2(const int* __restrict__ elem,
    const u16* __restrict__ h1, const u16* __restrict__ w2b,
    const float* __restrict__ b2, const int* __restrict__ pos, u16* __restrict__ hbuf)
{
  __shared__ u16 wl[16384];   // 32 frags x 64 lanes x 8 bf16, chunk (j2*4+t)*64+lane
  #pragma unroll
  for (int r = 0; r < 8; r++){
    int q = threadIdx.x + 256*r;
    int j2t = q >> 6, ln = q & 63;
    int cc = ln & 15, kk = ln >> 4;
    int j2 = j2t >> 2, tt = j2t & 3;
    *(s16x8*)(wl + (size_t)q*8) =
        *(const s16x8*)(w2b + (j2*16 + cc)*128 + tt*32 + kk*8);
  }

  const int lane = threadIdx.x & 63;
  const int col = lane & 15, kg = lane >> 4, b = lane & 3;
  const int p = kg >> 1;            // slot parity
  const int c0 = (kg & 1)*8;        // channel offset
  float bb[8];
  #pragma unroll
  for (int j2 = 0; j2 < 8; j2++) bb[j2] = b2[j2*16 + col];

  int wave = (int)((blockIdx.x*blockDim.x + threadIdx.x) >> 6);
  int g0 = wave, g1 = wave + 12288;
  int ma0 = g0*4 + (col >> 2), ma1 = g1*4 + (col >> 2);
  int me0 = g0*4 + kg,         me1 = g1*4 + kg;

  // all global loads issued up front
  int4 e0l = *(const int4*)(elem + ma0*8), e0h = *(const int4*)(elem + ma0*8 + 4);
  int4 e1l = *(const int4*)(elem + ma1*8), e1h = *(const int4*)(elem + ma1*8 + 4);
  int4 p0l = *(const int4*)(pos + me0*8),  p0h = *(const int4*)(pos + me0*8 + 4);
  int4 p1l = *(const int4*)(pos + me1*8),  p1h = *(const int4*)(pos + me1*8 + 4);

  int v00 = p ? e0l.y : e0l.x, v01 = p ? e0l.w : e0l.z;
  int v02 = p ? e0h.y : e0h.x, v03 = p ? e0h.w : e0h.z;
  int v10 = p ? e1l.y : e1l.x, v11 = p ? e1l.w : e1l.z;
  int v12 = p ? e1h.y : e1h.x, v13 = p ? e1h.w : e1h.z;

  s16x8 af0[4], af1[4];
  af0[0] = *(const s16x8*)(h1 + (size_t)v00*64 + b*16 + c0);
  af0[1] = *(const s16x8*)(h1 + (size_t)v01*64 + b*16 + c0);
  af0[2] = *(const s16x8*)(h1 + (size_t)v02*64 + b*16 + c0);
  af0[3] = *(const s16x8*)(h1 + (size_t)v03*64 + b*16 + c0);
  af1[0] = *(const s16x8*)(h1 + (size_t)v10*64 + b*16 + c0);
  af1[1] = *(const s16x8*)(h1 + (size_t)v11*64 + b*16 + c0);
  af1[2] = *(const s16x8*)(h1 + (size_t)v12*64 + b*16 + c0);
  af1[3] = *(const s16x8*)(h1 + (size_t)v13*64 + b*16 + c0);

  int pe0[8] = {p0l.x,p0l.y,p0l.z,p0l.w,p0h.x,p0h.y,p0h.z,p0h.w};
  int pe1[8] = {p1l.x,p1l.y,p1l.z,p1l.w,p1h.x,p1h.y,p1h.z,p1h.w};

  __syncthreads();   // W stage visible

  #pragma unroll
  for (int j2 = 0; j2 < 8; j2++){
    s16x8 w0 = *(const s16x8*)(wl + ((size_t)(j2*4 + 0)*64 + lane)*8);
    s16x8 w1 = *(const s16x8*)(wl + ((size_t)(j2*4 + 1)*64 + lane)*8);
    s16x8 w2 = *(const s16x8*)(wl + ((size_t)(j2*4 + 2)*64 + lane)*8);
    s16x8 w3 = *(const s16x8*)(wl + ((size_t)(j2*4 + 3)*64 + lane)*8);
    f32x4 c = {0.f,0.f,0.f,0.f};
    c = __builtin_amdgcn_mfma_f32_16x16x32_bf16(af0[0], w0, c, 0, 0, 0);
    c = __builtin_amdgcn_mfma_f32_16x16x32_bf16(af0[1], w1, c, 0, 0, 0);
    c = __builtin_amdgcn_mfma_f32_16x16x32_bf16(af0[2], w2, c, 0, 0, 0);
    c = __builtin_amdgcn_mfma_f32_16x16x32_bf16(af0[3], w3, c, 0, 0, 0);
    uint2 d; d.x = pk2(c[0]+bb[j2], c[1]+bb[j2]); d.y = pk2(c[2]+bb[j2], c[3]+bb[j2]);
    *(uint2*)(hbuf + (size_t)pe0[j2]*64 + col*4) = d;
  }
  #pragma unroll
  for (int j2 = 0; j2 < 8; j2++){
    s16x8 w0 = *(const s16x8*)(wl + ((size_t)(j2*4 + 0)*64 + lane)*8);
    s16x8 w1 = *(const s16x8*)(wl + ((size_t)(j2*4 + 1)*64 + lane)*8);
    s16x8 w2 = *(const s16x8*)(wl + ((size_t)(j2*4 + 2)*64 + lane)*8);
    s16x8 w3 = *(const s16x8*)(wl + ((size_t)(j2*4 + 3)*64 + lane)*8);
    f32x4 c = {0.f,0.f,0.f,0.f};
    c = __builtin_amdgcn_mfma_f32_16x16x32_bf16(af1[0], w0, c, 0, 0, 0);
    c = __builtin_amdgcn_mfma_f32_16x16x32_bf16(af1[1], w1, c, 0, 0, 0);
    c = __builtin_amdgcn_mfma_f32_16x16x32_bf16(af1[2], w2, c, 0, 0, 0);
    c = __builtin_amdgcn_mfma_f32_16x16x32_bf16(af1[3], w3, c, 0, 0, 0);
    uint2 d; d.x = pk2(c[0]+bb[j2], c[1]+bb[j2]); d.y = pk2(c[2]+bb[j2], c[3]+bb[j2]);
    *(uint2*)(hbuf + (size_t)pe1[j2]*64 + col*4) = d;
  }
}

// ---------- segmented reduce, 2 vertices interleaved per iteration ----------
__global__ __launch_bounds__(256) void k_reduce(const u16* __restrict__ hbuf,
    const int* __restrict__ rows, const int* __restrict__ cnt,
    float* __restrict__ acc, float* __restrict__ stat)
{
  int lane = threadIdx.x & 63, wid = threadIdx.x >> 6;
  int col = lane & 15, g = lane >> 4;
  int wv = (blockIdx.x*blockDim.x + threadIdx.x) >> 6;
  int nwv = (gridDim.x*blockDim.x) >> 6;
  float st_s = 0.f, st_q = 0.f;
  for (int v = wv; v < NV; v += 2*nwv){
    int v2 = v + nwv;
    bool hasB = (v2 < NV);
    int rsA = rows[v], cA = cnt[v];
    int rsB = hasB ? rows[v2] : 0, cB = hasB ? cnt[v2] : 0;
    const u16* baseA = hbuf + (size_t)rsA*64 + col*4;
    const u16* baseB = hbuf + (size_t)rsB*64 + col*4;
    float A0=0,A1=0,A2=0,A3=0,B0=0,B1=0,B2=0,B3=0;
    int cmax = cA > cB ? cA : cB;
    for (int p4 = 0; p4 < cmax; p4 += 8){
      int pa = p4 + g, pb = p4 + 4 + g;
      uint2 dAa={0u,0u}, dAb={0u,0u}, dBa={0u,0u}, dBb={0u,0u};
      if (pa < cA) dAa = *(const uint2*)(baseA + (size_t)pa*64);
      if (pb < cA) dAb = *(const uint2*)(baseA + (size_t)pb*64);
      if (pa < cB) dBa = *(const uint2*)(baseB + (size_t)pa*64);
      if (pb < cB) dBb = *(const uint2*)(baseB + (size_t)pb*64);
      A0 += bf2f_lo(dAa.x) + bf2f_lo(dAb.x);
      A1 += bf2f_hi(dAa.x) + bf2f_hi(dAb.x);
      A2 += bf2f_lo(dAa.y) + bf2f_lo(dAb.y);
      A3 += bf2f_hi(dAa.y) + bf2f_hi(dAb.y);
      B0 += bf2f_lo(dBa.x) + bf2f_lo(dBb.x);
      B1 += bf2f_hi(dBa.x) + bf2f_hi(dBb.x);
      B2 += bf2f_lo(dBa.y) + bf2f_lo(dBb.y);
      B3 += bf2f_hi(dBa.y) + bf2f_hi(dBb.y);
    }
    A0 += __shfl_xor(A0,16); A0 += __shfl_xor(A0,32);
    A1 += __shfl_xor(A1,16); A1 += __shfl_xor(A1,32);
    A2 += __shfl_xor(A2,16); A2 += __shfl_xor(A2,32);
    A3 += __shfl_xor(A3,16); A3 += __shfl_xor(A3,32);
    B0 += __shfl_xor(B0,16); B0 += __shfl_xor(B0,32);
    B1 += __shfl_xor(B1,16); B1 += __shfl_xor(B1,32);
    B2 += __shfl_xor(B2,16); B2 += __shfl_xor(B2,32);
    B3 += __shfl_xor(B3,16); B3 += __shfl_xor(B3,32);
    float invA = 1.0f / fmaxf((float)cA, 1.0f);
    float valA = (g==0 ? A0 : g==1 ? A1 : g==2 ? A2 : A3) * invA;
    acc[((size_t)g*NV + v)*16 + col] = valA;
    st_s += valA; st_q += valA*valA;
    if (hasB){
      float invB = 1.0f / fmaxf((float)cB, 1.0f);
      float valB = (g==0 ? B0 : g==1 ? B1 : g==2 ? B2 : B3) * invB;
      acc[((size_t)g*NV + v2)*16 + col] = valB;
      st_s += valB; st_q += valB*valB;
    }
  }
  st_s += __shfl_xor(st_s, 16); st_s += __shfl_xor(st_s, 32);
  st_q += __shfl_xor(st_q, 16); st_q += __shfl_xor(st_q, 32);
  __shared__ float ls[4][16], lq[4][16];
  if (lane < 16){ ls[wid][lane] = st_s; lq[wid][lane] = st_q; }
  __syncthreads();
  if (threadIdx.x < 32){
    int c2 = threadIdx.x & 15, which = threadIdx.x >> 4;
    float tot = 0.f;
    #pragma unroll
    for (int w = 0; w < 4; w++) tot += which ? lq[w][c2] : ls[w][c2];
    unsafeAtomicAdd(stat + which*16 + c2, tot);
  }
}

__global__ void k_finalize(float* __restrict__ stat, const float* __restrict__ gamma,
                           const float* __restrict__ beta)
{
  int co = threadIdx.x;
  if (co < 16){
    const float invn = 1.0f / (float)(NB*NV);
    float meanv = stat[co]*invn;
    float var   = stat[16+co]*invn - meanv*meanv;
    float sc = gamma[co]*rsqrtf(var + 1e-5f);
    stat[32+co] = sc;
    stat[48+co] = beta[co] - meanv*sc;
  }
}

// ---------- apply BN1 + relu -> h1[v][b][16] bf16 ----------
__global__ __launch_bounds__(256) void k_apply1(const float* __restrict__ acc,
    const float* __restrict__ stat, u16* __restrict__ h1)
{
  int idx = blockIdx.x*256 + threadIdx.x;
  int v = idx >> 2, b = idx & 3;
  if (v >= NV) return;
  const f32x4* a4 = (const f32x4*)(acc + ((size_t)b*NV + v)*16);
  u16 o[16] __attribute__((aligned(16)));
  #pragma unroll
  for (int k = 0; k < 4; k++){
    f32x4 vv = a4[k];
    #pragma unroll
    for (int t = 0; t < 4; t++){
      int co = k*4 + t;
      float val = vv[t]*stat[32+co] + stat[48+co];
      o[co] = f2bf(fmaxf(val, 0.f));
    }
  }
  uint4* dst = (uint4*)(h1 + (size_t)v*64 + b*16);
  dst[0] = *(uint4*)(o);
  dst[1] = *(uint4*)(o + 8);
}

// ---------- final: BN2 + skip GEMV + relu + transpose to [B][Co][N] ----------
__global__ __launch_bounds__(256) void k_final(const float* __restrict__ acc,
    const float* __restrict__ stat, const float* __restrict__ x,
    const float* __restrict__ wsk, const float* __restrict__ bsk, float* __restrict__ out)
{
  int n = blockIdx.x*blockDim.x + threadIdx.x;
  int b = blockIdx.y;
  if (n >= NV) return;
  float xv[8];
  #pragma unroll
  for (int c = 0; c < 8; c++) xv[c] = x[((size_t)b*8 + c)*NV + n];
  const f32x4* a4 = (const f32x4*)(acc + ((size_t)b*NV + n)*16);
  #pragma unroll
  for (int k = 0; k < 4; k++){
    f32x4 v = a4[k];
    #pragma unroll
    for (int t = 0; t < 4; t++){
      int co = k*4 + t;
      float val = v[t]*stat[32+co] + stat[48+co] + bsk[co];
      #pragma unroll
      for (int c = 0; c < 8; c++) val += wsk[co*8+c]*xv[c];
      out[((size_t)b*16 + co)*NV + n] = fmaxf(val, 0.f);
    }
  }
}

extern "C" void kernel_launch(void* const* d_in, const int* in_sizes, int n_in,
                              void* d_out, int out_size, void* d_ws, size_t ws_size,
                              hipStream_t stream) {
  const float* x    = (const float*)d_in[0];
  const int*   elem = (const int*)  d_in[1];
  const float* W1   = (const float*)d_in[2];
  const float* b1   = (const float*)d_in[3];
  const float* g1   = (const float*)d_in[4];
  const float* be1  = (const float*)d_in[5];
  const float* W2   = (const float*)d_in[6];
  const float* b2   = (const float*)d_in[7];
  const float* g2   = (const float*)d_in[8];
  const float* be2  = (const float*)d_in[9];
  const float* Wsk  = (const float*)d_in[10];
  const float* bsk  = (const float*)d_in[11];
  float* out = (float*)d_out;

  if (ws_size < (size_t)WS_NEED) return;  // visible failure rather than corruption

  char* ws = (char*)d_ws;
  int*   cnt  = (int*)  (ws + OFF_CNT);
  int*   next = (int*)  (ws + OFF_NEXT);
  float* stat = (float*)(ws + OFF_STAT);
  int*   rows = (int*)  (ws + OFF_ROWS);
  int*   bsum = (int*)  (ws + OFF_BSUM);
  int*   pos  = (int*)  (ws + OFF_POS);
  u16*   xtb  = (u16*)  (ws + OFF_XTB);
  u16*   w1b  = (u16*)  (ws + OFF_W1B);
  u16*   w2b  = (u16*)  (ws + OFF_W2B);
  u16*   h1   = (u16*)  (ws + OFF_H1);
  float* acc  = (float*)(ws + OFF_ACC);
  u16*   hbuf = (u16*)  (ws + OFF_HBUF);

  // zero cnt + next + stat (contiguous, ~0.8 MB)
  hipMemsetAsync(ws, 0, OFF_STAT + 384, stream);

  k_hist<<<1024, 256, 0, stream>>>(elem, W1, W2, cnt, w1b, w2b);
  k_xt<<<NBLK, 256, 0, stream>>>(x, xtb);
  k_scan_a<<<NBLK, 256, 0, stream>>>(cnt, bsum);
  k_scan_b<<<1, 64, 0, stream>>>(bsum);
  k_scan_c<<<NBLK, 256, 0, stream>>>(cnt, bsum, rows);
  k_pos<<<NPOS/256, 256, 0, stream>>>(elem, rows, next, pos);

  k_conv1<<<3072, 256, 0, stream>>>(elem, xtb, w1b, b1, pos, hbuf);
  k_reduce<<<2048, 256, 0, stream>>>(hbuf, rows, cnt, acc, stat);
  k_finalize<<<1, 64, 0, stream>>>(stat, g1, be1);
  k_apply1<<<(NV*4 + 255)/256, 256, 0, stream>>>(acc, stat, h1);

  hipMemsetAsync(stat, 0, 128, stream);  // re-zero sum/sq only

  k_conv2<<<3072, 256, 0, stream>>>(elem, h1, w2b, b2, pos, hbuf);
  k_reduce<<<2048, 256, 0, stream>>>(hbuf, rows, cnt, acc, stat);
  k_finalize<<<1, 64, 0, stream>>>(stat, g2, be2);
  k_final<<<dim3((NV+255)/256, NB), 256, 0, stream>>>(acc, stat, x, Wsk, bsk, out);
}

// Round 5
// 275.308 us; speedup vs baseline: 1.9455x; 1.0100x over previous
//
#include <hip/hip_runtime.h>

#define NB 4
#define CIN 8
#define CO 16
#define NV 100000
#define NM 98304
#define NPOS (NM*8)          // 786432
#define NBLK ((NV+255)/256)  // 391
#define RED_NWV 8192         // k_reduce waves: 2048 blocks x 4 waves (grid must match!)

typedef short s16x8 __attribute__((ext_vector_type(8)));
typedef float f32x4 __attribute__((ext_vector_type(4)));
typedef unsigned short u16;
typedef unsigned int u32;

// ---- ws layout (bytes, 128-aligned) ----
#define OFF_CNT   0                      // int cnt[NV]
#define OFF_NEXT  400128                 // int next[NV]
#define OFF_STAT  800256                 // float stat[64]
#define OFF_ROWS  800640                 // int row_start[NV]
#define OFF_BSUM  1200768                // int bsum[NBLK]
#define OFF_POS   1202432                // int pos[NPOS]
#define OFF_XTB   4348160                // bf16 xtb[NV][32]  ([v][b*8+c])
#define OFF_W1B   10748160               // bf16 w1[128][64]
#define OFF_W2B   10764544               // bf16 w2[128][128]
#define OFF_H1    10797312               // bf16 h1[NV][4][16]
#define OFF_ACC   23597312               // f32 acc[4][NV][16]
#define OFF_HBUF  49197312               // bf16 hbuf[NPOS][16col][4b] (128B rows)
#define WS_NEED   149860608

static __device__ __forceinline__ u16 f2bf(float f){
  union { float f; u32 u; } v; v.f = f;
  u32 r = v.u + 0x7fffu + ((v.u >> 16) & 1u);
  return (u16)(r >> 16);
}
static __device__ __forceinline__ float bf2f_lo(u32 w){
  union { u32 u; float f; } v; v.u = w << 16; return v.f;
}
static __device__ __forceinline__ float bf2f_hi(u32 w){
  union { u32 u; float f; } v; v.u = w & 0xffff0000u; return v.f;
}
static __device__ __forceinline__ u32 pk2(float a, float b){
  return (u32)f2bf(a) | (((u32)f2bf(b)) << 16);
}

// ---------- hist: element histogram + W->bf16 ----------
__global__ __launch_bounds__(256) void k_hist(const int* __restrict__ elem,
    const float* __restrict__ W1, const float* __restrict__ W2,
    int* __restrict__ cnt, u16* __restrict__ w1b, u16* __restrict__ w2b)
{
  const int T1 = NPOS;
  const int T2 = T1 + 128*64;
  const int T3 = T2 + 128*128;
  int stride = gridDim.x*blockDim.x;
  for (int i = blockIdx.x*blockDim.x + threadIdx.x; i < T3; i += stride){
    if (i < T1) { atomicAdd(cnt + elem[i], 1); }
    else if (i < T2){ int j = i - T1; w1b[j] = f2bf(W1[j]); }
    else { int j = i - T2; w2b[j] = f2bf(W2[j]); }
  }
}

// ---------- transpose x[32][NV] -> xtb[v][32] bf16 via LDS tile ----------
__global__ __launch_bounds__(256) void k_xt(const float* __restrict__ x, u16* __restrict__ xtb)
{
  __shared__ float tile[32][257];
  int t = threadIdx.x;
  int v0 = blockIdx.x*256;
  #pragma unroll
  for (int r = 0; r < 32; r++){
    int v = v0 + t;
    tile[r][t] = (v < NV) ? x[(size_t)r*NV + v] : 0.f;
  }
  __syncthreads();
  int v = v0 + t;
  if (v < NV){
    u16 o[32] __attribute__((aligned(16)));
    #pragma unroll
    for (int r = 0; r < 32; r++) o[r] = f2bf(tile[r][t]);
    uint4* dst = (uint4*)(xtb + (size_t)v*32);
    #pragma unroll
    for (int k = 0; k < 4; k++) dst[k] = *(uint4*)(o + k*8);
  }
}

// ---------- scan stage A: per-block sums ----------
__global__ __launch_bounds__(256) void k_scan_a(const int* __restrict__ cnt, int* __restrict__ bsum)
{
  int v = blockIdx.x*256 + threadIdx.x;
  int x = (v < NV) ? cnt[v] : 0;
  #pragma unroll
  for (int off = 32; off > 0; off >>= 1) x += __shfl_down(x, off);
  __shared__ int ls[4];
  int wid = threadIdx.x >> 6, lane = threadIdx.x & 63;
  if (lane == 0) ls[wid] = x;
  __syncthreads();
  if (threadIdx.x == 0) bsum[blockIdx.x] = ls[0] + ls[1] + ls[2] + ls[3];
}

// ---------- scan stage B: wave-parallel exclusive scan of block sums ----------
__global__ void k_scan_b(int* __restrict__ bsum)
{
  int lane = threadIdx.x & 63;
  int base = 0;
  for (int i0 = 0; i0 < NBLK; i0 += 64){
    int i = i0 + lane;
    int xv = (i < NBLK) ? bsum[i] : 0;
    int incl = xv;
    #pragma unroll
    for (int off = 1; off <= 32; off <<= 1){
      int y = __shfl_up(incl, off);
      if (lane >= off) incl += y;
    }
    if (i < NBLK) bsum[i] = base + incl - xv;
    base += __shfl(incl, 63);
  }
}

// ---------- scan stage C: block-local exclusive scan + offset -> row_start ----------
__global__ __launch_bounds__(256) void k_scan_c(const int* __restrict__ cnt,
    const int* __restrict__ bsum, int* __restrict__ rows)
{
  int v = blockIdx.x*256 + threadIdx.x;
  int x = (v < NV) ? cnt[v] : 0;
  int incl = x;
  #pragma unroll
  for (int off = 1; off <= 32; off <<= 1){
    int y = __shfl_up(incl, off);
    if ((threadIdx.x & 63) >= off) incl += y;
  }
  __shared__ int wt[4];
  int wid = threadIdx.x >> 6, lane = threadIdx.x & 63;
  if (lane == 63) wt[wid] = incl;
  __syncthreads();
  int woff = 0;
  for (int w = 0; w < 4; w++) if (w < wid) woff += wt[w];
  if (v < NV) rows[v] = bsum[blockIdx.x] + woff + incl - x;
}

// ---------- pos[i] = row_start[elem[i]] + running offset ----------
__global__ __launch_bounds__(256) void k_pos(const int* __restrict__ elem,
    const int* __restrict__ rows, int* __restrict__ next, int* __restrict__ pos)
{
  int i = blockIdx.x*256 + threadIdx.x;
  if (i < NPOS){
    int v = elem[i];
    int old = atomicAdd(next + v, 1);
    pos[i] = rows[v] + old;
  }
}

// ---------- conv1: one-shot, 2 groups/wave straight-line, W1 in regs ----------
// grid MUST be 3072 blocks x 256 (12288 waves; ngrp = 24576)
__global__ __launch_bounds__(256) void k_conv1(const int* __restrict__ elem,
    const u16* __restrict__ xtb, const u16* __restrict__ w1b,
    const float* __restrict__ b1, const int* __restrict__ pos, u16* __restrict__ hbuf)
{
  const int lane = threadIdx.x & 63;
  const int col = lane & 15, kg = lane >> 4, b = lane & 3;
  s16x8 wf[8][2];
  #pragma unroll
  for (int j2 = 0; j2 < 8; j2++)
    #pragma unroll
    for (int t = 0; t < 2; t++)
      wf[j2][t] = *(const s16x8*)(w1b + (j2*16 + col)*64 + t*32 + kg*8);
  float bb[8];
  #pragma unroll
  for (int j2 = 0; j2 < 8; j2++) bb[j2] = b1[j2*16 + col];

  int wave = (int)((blockIdx.x*blockDim.x + threadIdx.x) >> 6);
  int g0 = wave, g1 = wave + 12288;
  int ma0 = g0*4 + (col >> 2), ma1 = g1*4 + (col >> 2);
  int me0 = g0*4 + kg,         me1 = g1*4 + kg;

  int e00 = elem[ma0*8 + kg], e01 = elem[ma0*8 + 4 + kg];
  int e10 = elem[ma1*8 + kg], e11 = elem[ma1*8 + 4 + kg];
  int4 p0l = *(const int4*)(pos + me0*8), p0h = *(const int4*)(pos + me0*8 + 4);
  int4 p1l = *(const int4*)(pos + me1*8), p1h = *(const int4*)(pos + me1*8 + 4);
  s16x8 a00 = *(const s16x8*)(xtb + (size_t)e00*32 + b*8);
  s16x8 a01 = *(const s16x8*)(xtb + (size_t)e01*32 + b*8);
  s16x8 a10 = *(const s16x8*)(xtb + (size_t)e10*32 + b*8);
  s16x8 a11 = *(const s16x8*)(xtb + (size_t)e11*32 + b*8);

  int pe0[8] = {p0l.x,p0l.y,p0l.z,p0l.w,p0h.x,p0h.y,p0h.z,p0h.w};
  int pe1[8] = {p1l.x,p1l.y,p1l.z,p1l.w,p1h.x,p1h.y,p1h.z,p1h.w};

  #pragma unroll
  for (int j2 = 0; j2 < 8; j2++){
    f32x4 c = {0.f,0.f,0.f,0.f};
    c = __builtin_amdgcn_mfma_f32_16x16x32_bf16(a00, wf[j2][0], c, 0, 0, 0);
    c = __builtin_amdgcn_mfma_f32_16x16x32_bf16(a01, wf[j2][1], c, 0, 0, 0);
    uint2 d; d.x = pk2(c[0]+bb[j2], c[1]+bb[j2]); d.y = pk2(c[2]+bb[j2], c[3]+bb[j2]);
    *(uint2*)(hbuf + (size_t)pe0[j2]*64 + col*4) = d;
  }
  #pragma unroll
  for (int j2 = 0; j2 < 8; j2++){
    f32x4 c = {0.f,0.f,0.f,0.f};
    c = __builtin_amdgcn_mfma_f32_16x16x32_bf16(a10, wf[j2][0], c, 0, 0, 0);
    c = __builtin_amdgcn_mfma_f32_16x16x32_bf16(a11, wf[j2][1], c, 0, 0, 0);
    uint2 d; d.x = pk2(c[0]+bb[j2], c[1]+bb[j2]); d.y = pk2(c[2]+bb[j2], c[3]+bb[j2]);
    *(uint2*)(hbuf + (size_t)pe1[j2]*64 + col*4) = d;
  }
}

// ---------- conv2: one-shot, 2 groups/wave, W2 staged in LDS (frag order) ----------
// grid MUST be 3072 blocks x 256
__global__ __launch_bounds__(256) void k_conv2(const int* __restrict__ elem,
    const u16* __restrict__ h1, const u16* __restrict__ w2b,
    const float* __restrict__ b2, const int* __restrict__ pos, u16* __restrict__ hbuf)
{
  __shared__ u16 wl[16384];   // 32 frags x 64 lanes x 8 bf16, chunk (j2*4+t)*64+lane
  #pragma unroll
  for (int r = 0; r < 8; r++){
    int q = threadIdx.x + 256*r;
    int j2t = q >> 6, ln = q & 63;
    int cc = ln & 15, kk = ln >> 4;
    int j2 = j2t >> 2, tt = j2t & 3;
    *(s16x8*)(wl + (size_t)q*8) =
        *(const s16x8*)(w2b + (j2*16 + cc)*128 + tt*32 + kk*8);
  }

  const int lane = threadIdx.x & 63;
  const int col = lane & 15, kg = lane >> 4, b = lane & 3;
  const int p = kg >> 1;            // slot parity
  const int c0 = (kg & 1)*8;        // channel offset
  float bb[8];
  #pragma unroll
  for (int j2 = 0; j2 < 8; j2++) bb[j2] = b2[j2*16 + col];

  int wave = (int)((blockIdx.x*blockDim.x + threadIdx.x) >> 6);
  int g0 = wave, g1 = wave + 12288;
  int ma0 = g0*4 + (col >> 2), ma1 = g1*4 + (col >> 2);
  int me0 = g0*4 + kg,         me1 = g1*4 + kg;

  int4 e0l = *(const int4*)(elem + ma0*8), e0h = *(const int4*)(elem + ma0*8 + 4);
  int4 e1l = *(const int4*)(elem + ma1*8), e1h = *(const int4*)(elem + ma1*8 + 4);
  int4 p0l = *(const int4*)(pos + me0*8),  p0h = *(const int4*)(pos + me0*8 + 4);
  int4 p1l = *(const int4*)(pos + me1*8),  p1h = *(const int4*)(pos + me1*8 + 4);

  int v00 = p ? e0l.y : e0l.x, v01 = p ? e0l.w : e0l.z;
  int v02 = p ? e0h.y : e0h.x, v03 = p ? e0h.w : e0h.z;
  int v10 = p ? e1l.y : e1l.x, v11 = p ? e1l.w : e1l.z;
  int v12 = p ? e1h.y : e1h.x, v13 = p ? e1h.w : e1h.z;

  s16x8 af0[4], af1[4];
  af0[0] = *(const s16x8*)(h1 + (size_t)v00*64 + b*16 + c0);
  af0[1] = *(const s16x8*)(h1 + (size_t)v01*64 + b*16 + c0);
  af0[2] = *(const s16x8*)(h1 + (size_t)v02*64 + b*16 + c0);
  af0[3] = *(const s16x8*)(h1 + (size_t)v03*64 + b*16 + c0);
  af1[0] = *(const s16x8*)(h1 + (size_t)v10*64 + b*16 + c0);
  af1[1] = *(const s16x8*)(h1 + (size_t)v11*64 + b*16 + c0);
  af1[2] = *(const s16x8*)(h1 + (size_t)v12*64 + b*16 + c0);
  af1[3] = *(const s16x8*)(h1 + (size_t)v13*64 + b*16 + c0);

  int pe0[8] = {p0l.x,p0l.y,p0l.z,p0l.w,p0h.x,p0h.y,p0h.z,p0h.w};
  int pe1[8] = {p1l.x,p1l.y,p1l.z,p1l.w,p1h.x,p1h.y,p1h.z,p1h.w};

  __syncthreads();   // W stage visible

  #pragma unroll
  for (int j2 = 0; j2 < 8; j2++){
    s16x8 w0 = *(const s16x8*)(wl + ((size_t)(j2*4 + 0)*64 + lane)*8);
    s16x8 w1 = *(const s16x8*)(wl + ((size_t)(j2*4 + 1)*64 + lane)*8);
    s16x8 w2 = *(const s16x8*)(wl + ((size_t)(j2*4 + 2)*64 + lane)*8);
    s16x8 w3 = *(const s16x8*)(wl + ((size_t)(j2*4 + 3)*64 + lane)*8);
    f32x4 c = {0.f,0.f,0.f,0.f};
    c = __builtin_amdgcn_mfma_f32_16x16x32_bf16(af0[0], w0, c, 0, 0, 0);
    c = __builtin_amdgcn_mfma_f32_16x16x32_bf16(af0[1], w1, c, 0, 0, 0);
    c = __builtin_amdgcn_mfma_f32_16x16x32_bf16(af0[2], w2, c, 0, 0, 0);
    c = __builtin_amdgcn_mfma_f32_16x16x32_bf16(af0[3], w3, c, 0, 0, 0);
    uint2 d; d.x = pk2(c[0]+bb[j2], c[1]+bb[j2]); d.y = pk2(c[2]+bb[j2], c[3]+bb[j2]);
    *(uint2*)(hbuf + (size_t)pe0[j2]*64 + col*4) = d;
  }
  #pragma unroll
  for (int j2 = 0; j2 < 8; j2++){
    s16x8 w0 = *(const s16x8*)(wl + ((size_t)(j2*4 + 0)*64 + lane)*8);
    s16x8 w1 = *(const s16x8*)(wl + ((size_t)(j2*4 + 1)*64 + lane)*8);
    s16x8 w2 = *(const s16x8*)(wl + ((size_t)(j2*4 + 2)*64 + lane)*8);
    s16x8 w3 = *(const s16x8*)(wl + ((size_t)(j2*4 + 3)*64 + lane)*8);
    f32x4 c = {0.f,0.f,0.f,0.f};
    c = __builtin_amdgcn_mfma_f32_16x16x32_bf16(af1[0], w0, c, 0, 0, 0);
    c = __builtin_amdgcn_mfma_f32_16x16x32_bf16(af1[1], w1, c, 0, 0, 0);
    c = __builtin_amdgcn_mfma_f32_16x16x32_bf16(af1[2], w2, c, 0, 0, 0);
    c = __builtin_amdgcn_mfma_f32_16x16x32_bf16(af1[3], w3, c, 0, 0, 0);
    uint2 d; d.x = pk2(c[0]+bb[j2], c[1]+bb[j2]); d.y = pk2(c[2]+bb[j2], c[3]+bb[j2]);
    *(uint2*)(hbuf + (size_t)pe1[j2]*64 + col*4) = d;
  }
}

// ---------- segmented reduce: preloaded CSR bounds + 4-vertex ILP ----------
// grid MUST be 2048 blocks x 256 (RED_NWV waves); c = rows[v+1]-rows[v]
__global__ __launch_bounds__(256) void k_reduce(const u16* __restrict__ hbuf,
    const int* __restrict__ rows, float* __restrict__ acc, float* __restrict__ stat)
{
  int lane = threadIdx.x & 63, wid = threadIdx.x >> 6;
  int col = lane & 15, g = lane >> 4;
  int wv0 = (blockIdx.x*blockDim.x + threadIdx.x) >> 6;

  // lane k preloads CSR bounds for this wave's k-th vertex (v = wv0 + k*RED_NWV)
  int vk = wv0 + lane*RED_NWV;
  int r0 = 0, r1 = 0;
  if (lane < 13 && vk < NV){
    r0 = rows[vk];
    r1 = (vk + 1 < NV) ? rows[vk + 1] : NPOS;
  }

  float st_s = 0.f, st_q = 0.f;
  __shared__ float ls[4][16], lq[4][16];

  #pragma unroll
  for (int k0 = 0; k0 < 16; k0 += 4){
    int rs[4], cc[4];
    #pragma unroll
    for (int j = 0; j < 4; j++){
      rs[j] = __shfl(r0, k0 + j);
      cc[j] = __shfl(r1, k0 + j) - rs[j];
    }
    int cmax = max(max(cc[0], cc[1]), max(cc[2], cc[3]));

    float A[4][4];
    #pragma unroll
    for (int j = 0; j < 4; j++){ A[j][0]=0.f; A[j][1]=0.f; A[j][2]=0.f; A[j][3]=0.f; }

    const u16* base[4];
    #pragma unroll
    for (int j = 0; j < 4; j++) base[j] = hbuf + (size_t)rs[j]*64 + col*4;

    for (int p = 0; p < cmax; p += 8){
      #pragma unroll
      for (int j = 0; j < 4; j++){
        int pa = p + g, pb = p + 4 + g;
        uint2 da = {0u,0u}, db = {0u,0u};
        if (pa < cc[j]) da = *(const uint2*)(base[j] + (size_t)pa*64);
        if (pb < cc[j]) db = *(const uint2*)(base[j] + (size_t)pb*64);
        A[j][0] += bf2f_lo(da.x) + bf2f_lo(db.x);
        A[j][1] += bf2f_hi(da.x) + bf2f_hi(db.x);
        A[j][2] += bf2f_lo(da.y) + bf2f_lo(db.y);
        A[j][3] += bf2f_hi(da.y) + bf2f_hi(db.y);
      }
    }

    #pragma unroll
    for (int j = 0; j < 4; j++){
      int v = wv0 + (k0 + j)*RED_NWV;
      if (v >= NV) continue;
      float s0 = A[j][0], s1 = A[j][1], s2 = A[j][2], s3 = A[j][3];
      s0 += __shfl_xor(s0,16); s0 += __shfl_xor(s0,32);
      s1 += __shfl_xor(s1,16); s1 += __shfl_xor(s1,32);
      s2 += __shfl_xor(s2,16); s2 += __shfl_xor(s2,32);
      s3 += __shfl_xor(s3,16); s3 += __shfl_xor(s3,32);
      float inv = 1.0f / fmaxf((float)cc[j], 1.0f);
      float val = (g==0 ? s0 : g==1 ? s1 : g==2 ? s2 : s3) * inv;
      acc[((size_t)g*NV + v)*16 + col] = val;
      st_s += val; st_q += val*val;
    }
  }

  st_s += __shfl_xor(st_s, 16); st_s += __shfl_xor(st_s, 32);
  st_q += __shfl_xor(st_q, 16); st_q += __shfl_xor(st_q, 32);
  if (lane < 16){ ls[wid][lane] = st_s; lq[wid][lane] = st_q; }
  __syncthreads();
  if (threadIdx.x < 32){
    int c2 = threadIdx.x & 15, which = threadIdx.x >> 4;
    float tot = 0.f;
    #pragma unroll
    for (int w = 0; w < 4; w++) tot += which ? lq[w][c2] : ls[w][c2];
    unsafeAtomicAdd(stat + which*16 + c2, tot);
  }
}

__global__ void k_finalize(float* __restrict__ stat, const float* __restrict__ gamma,
                           const float* __restrict__ beta)
{
  int co = threadIdx.x;
  if (co < 16){
    const float invn = 1.0f / (float)(NB*NV);
    float meanv = stat[co]*invn;
    float var   = stat[16+co]*invn - meanv*meanv;
    float sc = gamma[co]*rsqrtf(var + 1e-5f);
    stat[32+co] = sc;
    stat[48+co] = beta[co] - meanv*sc;
  }
}

// ---------- apply BN1 + relu -> h1[v][b][16] bf16 ----------
__global__ __launch_bounds__(256) void k_apply1(const float* __restrict__ acc,
    const float* __restrict__ stat, u16* __restrict__ h1)
{
  int idx = blockIdx.x*256 + threadIdx.x;
  int v = idx >> 2, b = idx & 3;
  if (v >= NV) return;
  const f32x4* a4 = (const f32x4*)(acc + ((size_t)b*NV + v)*16);
  u16 o[16] __attribute__((aligned(16)));
  #pragma unroll
  for (int k = 0; k < 4; k++){
    f32x4 vv = a4[k];
    #pragma unroll
    for (int t = 0; t < 4; t++){
      int co = k*4 + t;
      float val = vv[t]*stat[32+co] + stat[48+co];
      o[co] = f2bf(fmaxf(val, 0.f));
    }
  }
  uint4* dst = (uint4*)(h1 + (size_t)v*64 + b*16);
  dst[0] = *(uint4*)(o);
  dst[1] = *(uint4*)(o + 8);
}

// ---------- final: BN2 + skip GEMV + relu + transpose to [B][Co][N] ----------
__global__ __launch_bounds__(256) void k_final(const float* __restrict__ acc,
    const float* __restrict__ stat, const float* __restrict__ x,
    const float* __restrict__ wsk, const float* __restrict__ bsk, float* __restrict__ out)
{
  int n = blockIdx.x*blockDim.x + threadIdx.x;
  int b = blockIdx.y;
  if (n >= NV) return;
  float xv[8];
  #pragma unroll
  for (int c = 0; c < 8; c++) xv[c] = x[((size_t)b*8 + c)*NV + n];
  const f32x4* a4 = (const f32x4*)(acc + ((size_t)b*NV + n)*16);
  #pragma unroll
  for (int k = 0; k < 4; k++){
    f32x4 v = a4[k];
    #pragma unroll
    for (int t = 0; t < 4; t++){
      int co = k*4 + t;
      float val = v[t]*stat[32+co] + stat[48+co] + bsk[co];
      #pragma unroll
      for (int c = 0; c < 8; c++) val += wsk[co*8+c]*xv[c];
      out[((size_t)b*16 + co)*NV + n] = fmaxf(val, 0.f);
    }
  }
}

extern "C" void kernel_launch(void* const* d_in, const int* in_sizes, int n_in,
                              void* d_out, int out_size, void* d_ws, size_t ws_size,
                              hipStream_t stream) {
  const float* x    = (const float*)d_in[0];
  const int*   elem = (const int*)  d_in[1];
  const float* W1   = (const float*)d_in[2];
  const float* b1   = (const float*)d_in[3];
  const float* g1   = (const float*)d_in[4];
  const float* be1  = (const float*)d_in[5];
  const float* W2   = (const float*)d_in[6];
  const float* b2   = (const float*)d_in[7];
  const float* g2   = (const float*)d_in[8];
  const float* be2  = (const float*)d_in[9];
  const float* Wsk  = (const float*)d_in[10];
  const float* bsk  = (const float*)d_in[11];
  float* out = (float*)d_out;

  if (ws_size < (size_t)WS_NEED) return;  // visible failure rather than corruption

  char* ws = (char*)d_ws;
  int*   cnt  = (int*)  (ws + OFF_CNT);
  int*   next = (int*)  (ws + OFF_NEXT);
  float* stat = (float*)(ws + OFF_STAT);
  int*   rows = (int*)  (ws + OFF_ROWS);
  int*   bsum = (int*)  (ws + OFF_BSUM);
  int*   pos  = (int*)  (ws + OFF_POS);
  u16*   xtb  = (u16*)  (ws + OFF_XTB);
  u16*   w1b  = (u16*)  (ws + OFF_W1B);
  u16*   w2b  = (u16*)  (ws + OFF_W2B);
  u16*   h1   = (u16*)  (ws + OFF_H1);
  float* acc  = (float*)(ws + OFF_ACC);
  u16*   hbuf = (u16*)  (ws + OFF_HBUF);

  // zero cnt + next + stat (contiguous, ~0.8 MB)
  hipMemsetAsync(ws, 0, OFF_STAT + 384, stream);

  k_hist<<<1024, 256, 0, stream>>>(elem, W1, W2, cnt, w1b, w2b);
  k_xt<<<NBLK, 256, 0, stream>>>(x, xtb);
  k_scan_a<<<NBLK, 256, 0, stream>>>(cnt, bsum);
  k_scan_b<<<1, 64, 0, stream>>>(bsum);
  k_scan_c<<<NBLK, 256, 0, stream>>>(cnt, bsum, rows);
  k_pos<<<NPOS/256, 256, 0, stream>>>(elem, rows, next, pos);

  k_conv1<<<3072, 256, 0, stream>>>(elem, xtb, w1b, b1, pos, hbuf);
  k_reduce<<<2048, 256, 0, stream>>>(hbuf, rows, acc, stat);
  k_finalize<<<1, 64, 0, stream>>>(stat, g1, be1);
  k_apply1<<<(NV*4 + 255)/256, 256, 0, stream>>>(acc, stat, h1);

  hipMemsetAsync(stat, 0, 128, stream);  // re-zero sum/sq only

  k_conv2<<<3072, 256, 0, stream>>>(elem, h1, w2b, b2, pos, hbuf);
  k_reduce<<<2048, 256, 0, stream>>>(hbuf, rows, acc, stat);
  k_finalize<<<1, 64, 0, stream>>>(stat, g2, be2);
  k_final<<<dim3((NV+255)/256, NB), 256, 0, stream>>>(acc, stat, x, Wsk, bsk, out);
}

// Round 6
// 265.376 us; speedup vs baseline: 2.0184x; 1.0374x over previous
//
#include <hip/hip_runtime.h>

#define NB 4
#define CIN 8
#define CO 16
#define NV 100000
#define NM 98304
#define NPOS (NM*8)          // 786432
#define NBLK ((NV+255)/256)  // 391
#define RED_NWV 8192         // k_reduce waves: 2048 blocks x 4 waves (grid must match!)

typedef short s16x8 __attribute__((ext_vector_type(8)));
typedef float f32x4 __attribute__((ext_vector_type(4)));
typedef unsigned short u16;
typedef unsigned int u32;

// ---- ws layout (bytes, 128-aligned) ----
#define OFF_CNT   0                      // int cnt[NV]
#define OFF_NEXT  400128                 // int next[NV]
#define OFF_STAT  800256                 // float stat[96]: BN1 sum16/sq16, BN2 sum16/sq16
#define OFF_ROWS  800640                 // int row_start[NV]
#define OFF_BSUM  1200768                // int bsum[NBLK]
#define OFF_POS   1202432                // int pos[NPOS]
#define OFF_XTB   4348160                // bf16 xtb[NV][32]  ([v][b*8+c])
#define OFF_W1B   10748160               // bf16 w1[128][64]
#define OFF_W2B   10764544               // bf16 w2[128][128]
#define OFF_H1    10797312               // bf16 h1[NV][4][16]
#define OFF_ACC   23597312               // f32 acc[4][NV][16]
#define OFF_HBUF  49197312               // bf16 hbuf[NPOS][16col][4b] (128B rows)
#define WS_NEED   149860608

static __device__ __forceinline__ u16 f2bf(float f){
  union { float f; u32 u; } v; v.f = f;
  u32 r = v.u + 0x7fffu + ((v.u >> 16) & 1u);
  return (u16)(r >> 16);
}
static __device__ __forceinline__ float bf2f_lo(u32 w){
  union { u32 u; float f; } v; v.u = w << 16; return v.f;
}
static __device__ __forceinline__ float bf2f_hi(u32 w){
  union { u32 u; float f; } v; v.u = w & 0xffff0000u; return v.f;
}
static __device__ __forceinline__ u32 pk2(float a, float b){
  return (u32)f2bf(a) | (((u32)f2bf(b)) << 16);
}

// ---------- prep: [blocks 0..NBLK) transpose x via LDS tile | [NBLK..) hist + W->bf16 ----------
__global__ __launch_bounds__(256) void k_prep(const int* __restrict__ elem,
    const float* __restrict__ x, const float* __restrict__ W1, const float* __restrict__ W2,
    int* __restrict__ cnt, u16* __restrict__ xtb, u16* __restrict__ w1b, u16* __restrict__ w2b)
{
  __shared__ float tile[32][257];
  if (blockIdx.x < NBLK){
    int t = threadIdx.x;
    int v0 = blockIdx.x*256;
    #pragma unroll
    for (int r = 0; r < 32; r++){
      int v = v0 + t;
      tile[r][t] = (v < NV) ? x[(size_t)r*NV + v] : 0.f;
    }
    __syncthreads();
    int v = v0 + t;
    if (v < NV){
      u16 o[32] __attribute__((aligned(16)));
      #pragma unroll
      for (int r = 0; r < 32; r++) o[r] = f2bf(tile[r][t]);
      uint4* dst = (uint4*)(xtb + (size_t)v*32);
      #pragma unroll
      for (int k = 0; k < 4; k++) dst[k] = *(uint4*)(o + k*8);
    }
  } else {
    const int T1 = NPOS;
    const int T2 = T1 + 128*64;
    const int T3 = T2 + 128*128;
    int stride = (gridDim.x - NBLK)*256;
    for (int i = (blockIdx.x - NBLK)*256 + threadIdx.x; i < T3; i += stride){
      if (i < T1) { atomicAdd(cnt + elem[i], 1); }
      else if (i < T2){ int j = i - T1; w1b[j] = f2bf(W1[j]); }
      else { int j = i - T2; w2b[j] = f2bf(W2[j]); }
    }
  }
}

// ---------- scan stage A: per-block raw sums ----------
__global__ __launch_bounds__(256) void k_scan_a(const int* __restrict__ cnt, int* __restrict__ bsum)
{
  int v = blockIdx.x*256 + threadIdx.x;
  int x = (v < NV) ? cnt[v] : 0;
  #pragma unroll
  for (int off = 32; off > 0; off >>= 1) x += __shfl_down(x, off);
  __shared__ int ls[4];
  int wid = threadIdx.x >> 6, lane = threadIdx.x & 63;
  if (lane == 0) ls[wid] = x;
  __syncthreads();
  if (threadIdx.x == 0) bsum[blockIdx.x] = ls[0] + ls[1] + ls[2] + ls[3];
}

// ---------- scan stage C: self-computed block base + local scan -> row_start ----------
__global__ __launch_bounds__(256) void k_scan_c(const int* __restrict__ cnt,
    const int* __restrict__ bsum, int* __restrict__ rows)
{
  int wid = threadIdx.x >> 6, lane = threadIdx.x & 63;
  int v = blockIdx.x*256 + threadIdx.x;
  int x = (v < NV) ? cnt[v] : 0;
  int incl = x;
  #pragma unroll
  for (int off = 1; off <= 32; off <<= 1){
    int y = __shfl_up(incl, off);
    if (lane >= off) incl += y;
  }
  __shared__ int wt[4];
  __shared__ int sbase;
  if (lane == 63) wt[wid] = incl;
  if (threadIdx.x < 64){
    int s = 0;
    for (int i = threadIdx.x; i < blockIdx.x; i += 64) s += bsum[i];
    #pragma unroll
    for (int off = 32; off > 0; off >>= 1) s += __shfl_down(s, off);
    if (threadIdx.x == 0) sbase = s;
  }
  __syncthreads();
  int woff = 0;
  for (int w = 0; w < 4; w++) if (w < wid) woff += wt[w];
  if (v < NV) rows[v] = sbase + woff + incl - x;
}

// ---------- pos[i] = row_start[elem[i]] + running offset ----------
__global__ __launch_bounds__(256) void k_pos(const int* __restrict__ elem,
    const int* __restrict__ rows, int* __restrict__ next, int* __restrict__ pos)
{
  int i = blockIdx.x*256 + threadIdx.x;
  if (i < NPOS){
    int v = elem[i];
    int old = atomicAdd(next + v, 1);
    pos[i] = rows[v] + old;
  }
}

// ---------- conv1: one-shot, 2 groups/wave straight-line, W1 in regs ----------
// grid MUST be 3072 blocks x 256 (12288 waves; ngrp = 24576)
__global__ __launch_bounds__(256) void k_conv1(const int* __restrict__ elem,
    const u16* __restrict__ xtb, const u16* __restrict__ w1b,
    const float* __restrict__ b1, const int* __restrict__ pos, u16* __restrict__ hbuf)
{
  const int lane = threadIdx.x & 63;
  const int col = lane & 15, kg = lane >> 4, b = lane & 3;
  s16x8 wf[8][2];
  #pragma unroll
  for (int j2 = 0; j2 < 8; j2++)
    #pragma unroll
    for (int t = 0; t < 2; t++)
      wf[j2][t] = *(const s16x8*)(w1b + (j2*16 + col)*64 + t*32 + kg*8);
  float bb[8];
  #pragma unroll
  for (int j2 = 0; j2 < 8; j2++) bb[j2] = b1[j2*16 + col];

  int wave = (int)((blockIdx.x*blockDim.x + threadIdx.x) >> 6);
  int g0 = wave, g1 = wave + 12288;
  int ma0 = g0*4 + (col >> 2), ma1 = g1*4 + (col >> 2);
  int me0 = g0*4 + kg,         me1 = g1*4 + kg;

  int e00 = elem[ma0*8 + kg], e01 = elem[ma0*8 + 4 + kg];
  int e10 = elem[ma1*8 + kg], e11 = elem[ma1*8 + 4 + kg];
  int4 p0l = *(const int4*)(pos + me0*8), p0h = *(const int4*)(pos + me0*8 + 4);
  int4 p1l = *(const int4*)(pos + me1*8), p1h = *(const int4*)(pos + me1*8 + 4);
  s16x8 a00 = *(const s16x8*)(xtb + (size_t)e00*32 + b*8);
  s16x8 a01 = *(const s16x8*)(xtb + (size_t)e01*32 + b*8);
  s16x8 a10 = *(const s16x8*)(xtb + (size_t)e10*32 + b*8);
  s16x8 a11 = *(const s16x8*)(xtb + (size_t)e11*32 + b*8);

  int pe0[8] = {p0l.x,p0l.y,p0l.z,p0l.w,p0h.x,p0h.y,p0h.z,p0h.w};
  int pe1[8] = {p1l.x,p1l.y,p1l.z,p1l.w,p1h.x,p1h.y,p1h.z,p1h.w};

  #pragma unroll
  for (int j2 = 0; j2 < 8; j2++){
    f32x4 c = {0.f,0.f,0.f,0.f};
    c = __builtin_amdgcn_mfma_f32_16x16x32_bf16(a00, wf[j2][0], c, 0, 0, 0);
    c = __builtin_amdgcn_mfma_f32_16x16x32_bf16(a01, wf[j2][1], c, 0, 0, 0);
    uint2 d; d.x = pk2(c[0]+bb[j2], c[1]+bb[j2]); d.y = pk2(c[2]+bb[j2], c[3]+bb[j2]);
    *(uint2*)(hbuf + (size_t)pe0[j2]*64 + col*4) = d;
  }
  #pragma unroll
  for (int j2 = 0; j2 < 8; j2++){
    f32x4 c = {0.f,0.f,0.f,0.f};
    c = __builtin_amdgcn_mfma_f32_16x16x32_bf16(a10, wf[j2][0], c, 0, 0, 0);
    c = __builtin_amdgcn_mfma_f32_16x16x32_bf16(a11, wf[j2][1], c, 0, 0, 0);
    uint2 d; d.x = pk2(c[0]+bb[j2], c[1]+bb[j2]); d.y = pk2(c[2]+bb[j2], c[3]+bb[j2]);
    *(uint2*)(hbuf + (size_t)pe1[j2]*64 + col*4) = d;
  }
}

// ---------- conv2: one-shot, 2 groups/wave, W2 staged in LDS (frag order) ----------
// grid MUST be 3072 blocks x 256
__global__ __launch_bounds__(256) void k_conv2(const int* __restrict__ elem,
    const u16* __restrict__ h1, const u16* __restrict__ w2b,
    const float* __restrict__ b2, const int* __restrict__ pos, u16* __restrict__ hbuf)
{
  __shared__ u16 wl[16384];   // 32 frags x 64 lanes x 8 bf16, chunk (j2*4+t)*64+lane
  #pragma unroll
  for (int r = 0; r < 8; r++){
    int q = threadIdx.x + 256*r;
    int j2t = q >> 6, ln = q & 63;
    int cc = ln & 15, kk = ln >> 4;
    int j2 = j2t >> 2, tt = j2t & 3;
    *(s16x8*)(wl + (size_t)q*8) =
        *(const s16x8*)(w2b + (j2*16 + cc)*128 + tt*32 + kk*8);
  }

  const int lane = threadIdx.x & 63;
  const int col = lane & 15, kg = lane >> 4, b = lane & 3;
  const int p = kg >> 1;            // slot parity
  const int c0 = (kg & 1)*8;        // channel offset
  float bb[8];
  #pragma unroll
  for (int j2 = 0; j2 < 8; j2++) bb[j2] = b2[j2*16 + col];

  int wave = (int)((blockIdx.x*blockDim.x + threadIdx.x) >> 6);
  int g0 = wave, g1 = wave + 12288;
  int ma0 = g0*4 + (col >> 2), ma1 = g1*4 + (col >> 2);
  int me0 = g0*4 + kg,         me1 = g1*4 + kg;

  int4 e0l = *(const int4*)(elem + ma0*8), e0h = *(const int4*)(elem + ma0*8 + 4);
  int4 e1l = *(const int4*)(elem + ma1*8), e1h = *(const int4*)(elem + ma1*8 + 4);
  int4 p0l = *(const int4*)(pos + me0*8),  p0h = *(const int4*)(pos + me0*8 + 4);
  int4 p1l = *(const int4*)(pos + me1*8),  p1h = *(const int4*)(pos + me1*8 + 4);

  int v00 = p ? e0l.y : e0l.x, v01 = p ? e0l.w : e0l.z;
  int v02 = p ? e0h.y : e0h.x, v03 = p ? e0h.w : e0h.z;
  int v10 = p ? e1l.y : e1l.x, v11 = p ? e1l.w : e1l.z;
  int v12 = p ? e1h.y : e1h.x, v13 = p ? e1h.w : e1h.z;

  s16x8 af0[4], af1[4];
  af0[0] = *(const s16x8*)(h1 + (size_t)v00*64 + b*16 + c0);
  af0[1] = *(const s16x8*)(h1 + (size_t)v01*64 + b*16 + c0);
  af0[2] = *(const s16x8*)(h1 + (size_t)v02*64 + b*16 + c0);
  af0[3] = *(const s16x8*)(h1 + (size_t)v03*64 + b*16 + c0);
  af1[0] = *(const s16x8*)(h1 + (size_t)v10*64 + b*16 + c0);
  af1[1] = *(const s16x8*)(h1 + (size_t)v11*64 + b*16 + c0);
  af1[2] = *(const s16x8*)(h1 + (size_t)v12*64 + b*16 + c0);
  af1[3] = *(const s16x8*)(h1 + (size_t)v13*64 + b*16 + c0);

  int pe0[8] = {p0l.x,p0l.y,p0l.z,p0l.w,p0h.x,p0h.y,p0h.z,p0h.w};
  int pe1[8] = {p1l.x,p1l.y,p1l.z,p1l.w,p1h.x,p1h.y,p1h.z,p1h.w};

  __syncthreads();   // W stage visible

  #pragma unroll
  for (int j2 = 0; j2 < 8; j2++){
    s16x8 w0 = *(const s16x8*)(wl + ((size_t)(j2*4 + 0)*64 + lane)*8);
    s16x8 w1 = *(const s16x8*)(wl + ((size_t)(j2*4 + 1)*64 + lane)*8);
    s16x8 w2 = *(const s16x8*)(wl + ((size_t)(j2*4 + 2)*64 + lane)*8);
    s16x8 w3 = *(const s16x8*)(wl + ((size_t)(j2*4 + 3)*64 + lane)*8);
    f32x4 c = {0.f,0.f,0.f,0.f};
    c = __builtin_amdgcn_mfma_f32_16x16x32_bf16(af0[0], w0, c, 0, 0, 0);
    c = __builtin_amdgcn_mfma_f32_16x16x32_bf16(af0[1], w1, c, 0, 0, 0);
    c = __builtin_amdgcn_mfma_f32_16x16x32_bf16(af0[2], w2, c, 0, 0, 0);
    c = __builtin_amdgcn_mfma_f32_16x16x32_bf16(af0[3], w3, c, 0, 0, 0);
    uint2 d; d.x = pk2(c[0]+bb[j2], c[1]+bb[j2]); d.y = pk2(c[2]+bb[j2], c[3]+bb[j2]);
    *(uint2*)(hbuf + (size_t)pe0[j2]*64 + col*4) = d;
  }
  #pragma unroll
  for (int j2 = 0; j2 < 8; j2++){
    s16x8 w0 = *(const s16x8*)(wl + ((size_t)(j2*4 + 0)*64 + lane)*8);
    s16x8 w1 = *(const s16x8*)(wl + ((size_t)(j2*4 + 1)*64 + lane)*8);
    s16x8 w2 = *(const s16x8*)(wl + ((size_t)(j2*4 + 2)*64 + lane)*8);
    s16x8 w3 = *(const s16x8*)(wl + ((size_t)(j2*4 + 3)*64 + lane)*8);
    f32x4 c = {0.f,0.f,0.f,0.f};
    c = __builtin_amdgcn_mfma_f32_16x16x32_bf16(af1[0], w0, c, 0, 0, 0);
    c = __builtin_amdgcn_mfma_f32_16x16x32_bf16(af1[1], w1, c, 0, 0, 0);
    c = __builtin_amdgcn_mfma_f32_16x16x32_bf16(af1[2], w2, c, 0, 0, 0);
    c = __builtin_amdgcn_mfma_f32_16x16x32_bf16(af1[3], w3, c, 0, 0, 0);
    uint2 d; d.x = pk2(c[0]+bb[j2], c[1]+bb[j2]); d.y = pk2(c[2]+bb[j2], c[3]+bb[j2]);
    *(uint2*)(hbuf + (size_t)pe1[j2]*64 + col*4) = d;
  }
}

// ---------- segmented reduce: 16B lane loads (wave eats 8 rows/instr) ----------
// grid MUST be 2048 blocks x 256 (RED_NWV waves)
// lane L: col-pair k8 = L&7 (cols 2k8, 2k8+1), row-group rg = L>>3
__global__ __launch_bounds__(256) void k_reduce(const u16* __restrict__ hbuf,
    const int* __restrict__ rows, float* __restrict__ acc, float* __restrict__ stat)
{
  int lane = threadIdx.x & 63, wid = threadIdx.x >> 6;
  int k8 = lane & 7, rg = lane >> 3;
  int wv0 = (blockIdx.x*blockDim.x + threadIdx.x) >> 6;

  // lane k preloads CSR bounds for this wave's k-th vertex
  int vk = wv0 + lane*RED_NWV;
  int r0 = 0, r1 = 0;
  if (lane < 13 && vk < NV){
    r0 = rows[vk];
    r1 = (vk + 1 < NV) ? rows[vk + 1] : NPOS;
  }

  float st_s0 = 0.f, st_s1 = 0.f, st_q0 = 0.f, st_q1 = 0.f;

  #pragma unroll
  for (int k0 = 0; k0 < 16; k0 += 2){
    int rsA = __shfl(r0, k0),     cA = __shfl(r1, k0)     - rsA;
    int rsB = __shfl(r0, k0 + 1), cB = __shfl(r1, k0 + 1) - rsB;
    int vA = wv0 + k0*RED_NWV, vB = wv0 + (k0 + 1)*RED_NWV;

    float a0=0,a1=0,a2=0,a3=0,a4=0,a5=0,a6=0,a7=0;
    float b0=0,b1=0,b2=0,b3=0,b4=0,b5=0,b6=0,b7=0;
    const u16* pA = hbuf + (size_t)rsA*64 + lane*8;
    const u16* pB = hbuf + (size_t)rsB*64 + lane*8;
    int cm = max(cA, cB);
    for (int p = 0; p < cm; p += 8){
      uint4 dA = {0u,0u,0u,0u}, dB = {0u,0u,0u,0u};
      if (p + rg < cA) dA = *(const uint4*)(pA + (size_t)p*64);
      if (p + rg < cB) dB = *(const uint4*)(pB + (size_t)p*64);
      a0 += bf2f_lo(dA.x); a1 += bf2f_hi(dA.x); a2 += bf2f_lo(dA.y); a3 += bf2f_hi(dA.y);
      a4 += bf2f_lo(dA.z); a5 += bf2f_hi(dA.z); a6 += bf2f_lo(dA.w); a7 += bf2f_hi(dA.w);
      b0 += bf2f_lo(dB.x); b1 += bf2f_hi(dB.x); b2 += bf2f_lo(dB.y); b3 += bf2f_hi(dB.y);
      b4 += bf2f_lo(dB.z); b5 += bf2f_hi(dB.z); b6 += bf2f_lo(dB.w); b7 += bf2f_hi(dB.w);
    }
    // fold the 8 row-groups (lanes stride 8): xor 8, 16, 32
    #pragma unroll
    for (int off = 8; off <= 32; off <<= 1){
      a0 += __shfl_xor(a0, off); a1 += __shfl_xor(a1, off);
      a2 += __shfl_xor(a2, off); a3 += __shfl_xor(a3, off);
      a4 += __shfl_xor(a4, off); a5 += __shfl_xor(a5, off);
      a6 += __shfl_xor(a6, off); a7 += __shfl_xor(a7, off);
      b0 += __shfl_xor(b0, off); b1 += __shfl_xor(b1, off);
      b2 += __shfl_xor(b2, off); b3 += __shfl_xor(b3, off);
      b4 += __shfl_xor(b4, off); b5 += __shfl_xor(b5, off);
      b6 += __shfl_xor(b6, off); b7 += __shfl_xor(b7, off);
    }
    if (lane < 8){
      // lane k8 holds sums for col 2k8 (a0..a3 = b0..b3 batches) and col 2k8+1 (a4..a7)
      if (vA < NV){
        float inv = 1.0f / fmaxf((float)cA, 1.0f);
        float c0b[4] = {a0*inv, a1*inv, a2*inv, a3*inv};
        float c1b[4] = {a4*inv, a5*inv, a6*inv, a7*inv};
        #pragma unroll
        for (int q = 0; q < 4; q++){
          float2 w2; w2.x = c0b[q]; w2.y = c1b[q];
          *(float2*)(acc + ((size_t)q*NV + vA)*16 + 2*k8) = w2;
          st_s0 += c0b[q]; st_q0 += c0b[q]*c0b[q];
          st_s1 += c1b[q]; st_q1 += c1b[q]*c1b[q];
        }
      }
      if (vB < NV){
        float inv = 1.0f / fmaxf((float)cB, 1.0f);
        float c0b[4] = {b0*inv, b1*inv, b2*inv, b3*inv};
        float c1b[4] = {b4*inv, b5*inv, b6*inv, b7*inv};
        #pragma unroll
        for (int q = 0; q < 4; q++){
          float2 w2; w2.x = c0b[q]; w2.y = c1b[q];
          *(float2*)(acc + ((size_t)q*NV + vB)*16 + 2*k8) = w2;
          st_s0 += c0b[q]; st_q0 += c0b[q]*c0b[q];
          st_s1 += c1b[q]; st_q1 += c1b[q]*c1b[q];
        }
      }
    }
  }

  __shared__ float ls[4][16], lq[4][16];
  if (lane < 8){
    ls[wid][2*k8] = st_s0; ls[wid][2*k8+1] = st_s1;
    lq[wid][2*k8] = st_q0; lq[wid][2*k8+1] = st_q1;
  }
  __syncthreads();
  if (threadIdx.x < 32){
    int c2 = threadIdx.x & 15, which = threadIdx.x >> 4;
    float tot = 0.f;
    #pragma unroll
    for (int w = 0; w < 4; w++) tot += which ? lq[w][c2] : ls[w][c2];
    unsafeAtomicAdd(stat + which*16 + c2, tot);
  }
}

// ---------- apply BN1 (inline finalize) + relu -> h1[v][b][16] bf16 ----------
__global__ __launch_bounds__(256) void k_apply1(const float* __restrict__ acc,
    const float* __restrict__ stat, const float* __restrict__ gamma,
    const float* __restrict__ beta, u16* __restrict__ h1)
{
  __shared__ float sc[16], sh[16];
  if (threadIdx.x < 16){
    int co = threadIdx.x;
    const float invn = 1.0f / (float)(NB*NV);
    float m = stat[co]*invn;
    float var = stat[16+co]*invn - m*m;
    float s = gamma[co]*rsqrtf(var + 1e-5f);
    sc[co] = s; sh[co] = beta[co] - m*s;
  }
  __syncthreads();
  int idx = blockIdx.x*256 + threadIdx.x;
  int v = idx >> 2, b = idx & 3;
  if (v >= NV) return;
  const f32x4* a4 = (const f32x4*)(acc + ((size_t)b*NV + v)*16);
  u16 o[16] __attribute__((aligned(16)));
  #pragma unroll
  for (int k = 0; k < 4; k++){
    f32x4 vv = a4[k];
    #pragma unroll
    for (int t = 0; t < 4; t++){
      int co = k*4 + t;
      float val = vv[t]*sc[co] + sh[co];
      o[co] = f2bf(fmaxf(val, 0.f));
    }
  }
  uint4* dst = (uint4*)(h1 + (size_t)v*64 + b*16);
  dst[0] = *(uint4*)(o);
  dst[1] = *(uint4*)(o + 8);
}

// ---------- final: BN2 (inline finalize) + skip GEMV + relu + transpose ----------
__global__ __launch_bounds__(256) void k_final(const float* __restrict__ acc,
    const float* __restrict__ stat, const float* __restrict__ gamma,
    const float* __restrict__ beta, const float* __restrict__ x,
    const float* __restrict__ wsk, const float* __restrict__ bsk, float* __restrict__ out)
{
  __shared__ float sc[16], sh[16];
  if (threadIdx.x < 16){
    int co = threadIdx.x;
    const float invn = 1.0f / (float)(NB*NV);
    float m = stat[co]*invn;
    float var = stat[16+co]*invn - m*m;
    float s = gamma[co]*rsqrtf(var + 1e-5f);
    sc[co] = s; sh[co] = beta[co] - m*s + bsk[co];
  }
  __syncthreads();
  int n = blockIdx.x*blockDim.x + threadIdx.x;
  int b = blockIdx.y;
  if (n >= NV) return;
  float xv[8];
  #pragma unroll
  for (int c = 0; c < 8; c++) xv[c] = x[((size_t)b*8 + c)*NV + n];
  const f32x4* a4 = (const f32x4*)(acc + ((size_t)b*NV + n)*16);
  #pragma unroll
  for (int k = 0; k < 4; k++){
    f32x4 v = a4[k];
    #pragma unroll
    for (int t = 0; t < 4; t++){
      int co = k*4 + t;
      float val = v[t]*sc[co] + sh[co];
      #pragma unroll
      for (int c = 0; c < 8; c++) val += wsk[co*8+c]*xv[c];
      out[((size_t)b*16 + co)*NV + n] = fmaxf(val, 0.f);
    }
  }
}

extern "C" void kernel_launch(void* const* d_in, const int* in_sizes, int n_in,
                              void* d_out, int out_size, void* d_ws, size_t ws_size,
                              hipStream_t stream) {
  const float* x    = (const float*)d_in[0];
  const int*   elem = (const int*)  d_in[1];
  const float* W1   = (const float*)d_in[2];
  const float* b1   = (const float*)d_in[3];
  const float* g1   = (const float*)d_in[4];
  const float* be1  = (const float*)d_in[5];
  const float* W2   = (const float*)d_in[6];
  const float* b2   = (const float*)d_in[7];
  const float* g2   = (const float*)d_in[8];
  const float* be2  = (const float*)d_in[9];
  const float* Wsk  = (const float*)d_in[10];
  const float* bsk  = (const float*)d_in[11];
  float* out = (float*)d_out;

  if (ws_size < (size_t)WS_NEED) return;  // visible failure rather than corruption

  char* ws = (char*)d_ws;
  int*   cnt  = (int*)  (ws + OFF_CNT);
  int*   next = (int*)  (ws + OFF_NEXT);
  float* stat = (float*)(ws + OFF_STAT);   // [0..31] BN1, [32..63] BN2
  int*   rows = (int*)  (ws + OFF_ROWS);
  int*   bsum = (int*)  (ws + OFF_BSUM);
  int*   pos  = (int*)  (ws + OFF_POS);
  u16*   xtb  = (u16*)  (ws + OFF_XTB);
  u16*   w1b  = (u16*)  (ws + OFF_W1B);
  u16*   w2b  = (u16*)  (ws + OFF_W2B);
  u16*   h1   = (u16*)  (ws + OFF_H1);
  float* acc  = (float*)(ws + OFF_ACC);
  u16*   hbuf = (u16*)  (ws + OFF_HBUF);

  // zero cnt + next + stat (contiguous, ~0.8 MB)
  hipMemsetAsync(ws, 0, OFF_STAT + 384, stream);

  k_prep<<<NBLK + 1024, 256, 0, stream>>>(elem, x, W1, W2, cnt, xtb, w1b, w2b);
  k_scan_a<<<NBLK, 256, 0, stream>>>(cnt, bsum);
  k_scan_c<<<NBLK, 256, 0, stream>>>(cnt, bsum, rows);
  k_pos<<<NPOS/256, 256, 0, stream>>>(elem, rows, next, pos);

  k_conv1<<<3072, 256, 0, stream>>>(elem, xtb, w1b, b1, pos, hbuf);
  k_reduce<<<2048, 256, 0, stream>>>(hbuf, rows, acc, stat);
  k_apply1<<<(NV*4 + 255)/256, 256, 0, stream>>>(acc, stat, g1, be1, h1);

  k_conv2<<<3072, 256, 0, stream>>>(elem, h1, w2b, b2, pos, hbuf);
  k_reduce<<<2048, 256, 0, stream>>>(hbuf, rows, acc, stat + 32);
  k_final<<<dim3((NV+255)/256, NB), 256, 0, stream>>>(acc, stat + 32, g2, be2, x, Wsk, bsk, out);
}

// Round 7
// 259.624 us; speedup vs baseline: 2.0631x; 1.0222x over previous
//
#include <hip/hip_runtime.h>

#define NB 4
#define CIN 8
#define CO 16
#define NV 100000
#define NM 98304
#define NPOS (NM*8)          // 786432
#define NBLK ((NV+255)/256)  // 391
#define VPW 14               // vertices per wave in k_reduce
#define REDB 1786            // k_reduce blocks: 1786*4 waves * 14 >= NV (grid must match!)

typedef short s16x8 __attribute__((ext_vector_type(8)));
typedef float f32x4 __attribute__((ext_vector_type(4)));
typedef unsigned short u16;
typedef unsigned int u32;

// ---- ws layout (bytes, 128-aligned) ----
#define OFF_CNT   0                      // int cnt[NV]
#define OFF_NEXT  400128                 // int next[NV]
#define OFF_STAT  800256                 // float stat[96]: BN1 sum16/sq16, BN2 sum16/sq16
#define OFF_ROWS  800640                 // int row_start[NV]
#define OFF_BSUM  1200768                // int bsum[NBLK]
#define OFF_POS   1202432                // int pos[NPOS]
#define OFF_XTB   4348160                // bf16 xtb[NV][32]  ([v][b*8+c])
#define OFF_W1B   10748160               // bf16 w1[128][64]
#define OFF_W2B   10764544               // bf16 w2[128][128]
#define OFF_H1    10797312               // bf16 h1[NV][4][16]
#define OFF_MBUF  23597312               // bf16 mbuf[NV][4][16] (means, 12.8 MB)
#define OFF_HBUF  49197312               // bf16 hbuf[NPOS][16col][4b] (128B rows)
#define WS_NEED   149860608

static __device__ __forceinline__ u16 f2bf(float f){
  union { float f; u32 u; } v; v.f = f;
  u32 r = v.u + 0x7fffu + ((v.u >> 16) & 1u);
  return (u16)(r >> 16);
}
static __device__ __forceinline__ float bf2f_lo(u32 w){
  union { u32 u; float f; } v; v.u = w << 16; return v.f;
}
static __device__ __forceinline__ float bf2f_hi(u32 w){
  union { u32 u; float f; } v; v.u = w & 0xffff0000u; return v.f;
}
static __device__ __forceinline__ u32 pk2(float a, float b){
  return (u32)f2bf(a) | (((u32)f2bf(b)) << 16);
}

// ---------- prep: [blocks 0..NBLK) transpose x via LDS tile | [NBLK..) hist + W->bf16 ----------
__global__ __launch_bounds__(256) void k_prep(const int* __restrict__ elem,
    const float* __restrict__ x, const float* __restrict__ W1, const float* __restrict__ W2,
    int* __restrict__ cnt, u16* __restrict__ xtb, u16* __restrict__ w1b, u16* __restrict__ w2b)
{
  __shared__ float tile[32][257];
  if (blockIdx.x < NBLK){
    int t = threadIdx.x;
    int v0 = blockIdx.x*256;
    #pragma unroll
    for (int r = 0; r < 32; r++){
      int v = v0 + t;
      tile[r][t] = (v < NV) ? x[(size_t)r*NV + v] : 0.f;
    }
    __syncthreads();
    int v = v0 + t;
    if (v < NV){
      u16 o[32] __attribute__((aligned(16)));
      #pragma unroll
      for (int r = 0; r < 32; r++) o[r] = f2bf(tile[r][t]);
      uint4* dst = (uint4*)(xtb + (size_t)v*32);
      #pragma unroll
      for (int k = 0; k < 4; k++) dst[k] = *(uint4*)(o + k*8);
    }
  } else {
    const int T1 = NPOS;
    const int T2 = T1 + 128*64;
    const int T3 = T2 + 128*128;
    int stride = (gridDim.x - NBLK)*256;
    for (int i = (blockIdx.x - NBLK)*256 + threadIdx.x; i < T3; i += stride){
      if (i < T1) { atomicAdd(cnt + elem[i], 1); }
      else if (i < T2){ int j = i - T1; w1b[j] = f2bf(W1[j]); }
      else { int j = i - T2; w2b[j] = f2bf(W2[j]); }
    }
  }
}

// ---------- scan stage A: per-block raw sums ----------
__global__ __launch_bounds__(256) void k_scan_a(const int* __restrict__ cnt, int* __restrict__ bsum)
{
  int v = blockIdx.x*256 + threadIdx.x;
  int x = (v < NV) ? cnt[v] : 0;
  #pragma unroll
  for (int off = 32; off > 0; off >>= 1) x += __shfl_down(x, off);
  __shared__ int ls[4];
  int wid = threadIdx.x >> 6, lane = threadIdx.x & 63;
  if (lane == 0) ls[wid] = x;
  __syncthreads();
  if (threadIdx.x == 0) bsum[blockIdx.x] = ls[0] + ls[1] + ls[2] + ls[3];
}

// ---------- scan stage C: self-computed block base + local scan -> row_start ----------
__global__ __launch_bounds__(256) void k_scan_c(const int* __restrict__ cnt,
    const int* __restrict__ bsum, int* __restrict__ rows)
{
  int wid = threadIdx.x >> 6, lane = threadIdx.x & 63;
  int v = blockIdx.x*256 + threadIdx.x;
  int x = (v < NV) ? cnt[v] : 0;
  int incl = x;
  #pragma unroll
  for (int off = 1; off <= 32; off <<= 1){
    int y = __shfl_up(incl, off);
    if (lane >= off) incl += y;
  }
  __shared__ int wt[4];
  __shared__ int sbase;
  if (lane == 63) wt[wid] = incl;
  if (threadIdx.x < 64){
    int s = 0;
    for (int i = threadIdx.x; i < blockIdx.x; i += 64) s += bsum[i];
    #pragma unroll
    for (int off = 32; off > 0; off >>= 1) s += __shfl_down(s, off);
    if (threadIdx.x == 0) sbase = s;
  }
  __syncthreads();
  int woff = 0;
  for (int w = 0; w < 4; w++) if (w < wid) woff += wt[w];
  if (v < NV) rows[v] = sbase + woff + incl - x;
}

// ---------- pos[i] = row_start[elem[i]] + running offset ----------
__global__ __launch_bounds__(256) void k_pos(const int* __restrict__ elem,
    const int* __restrict__ rows, int* __restrict__ next, int* __restrict__ pos)
{
  int i = blockIdx.x*256 + threadIdx.x;
  if (i < NPOS){
    int v = elem[i];
    int old = atomicAdd(next + v, 1);
    pos[i] = rows[v] + old;
  }
}

// ---------- conv1: one-shot, 2 groups/wave straight-line, W1 in regs ----------
// grid MUST be 3072 blocks x 256 (12288 waves; ngrp = 24576)
__global__ __launch_bounds__(256) void k_conv1(const int* __restrict__ elem,
    const u16* __restrict__ xtb, const u16* __restrict__ w1b,
    const float* __restrict__ b1, const int* __restrict__ pos, u16* __restrict__ hbuf)
{
  const int lane = threadIdx.x & 63;
  const int col = lane & 15, kg = lane >> 4, b = lane & 3;
  s16x8 wf[8][2];
  #pragma unroll
  for (int j2 = 0; j2 < 8; j2++)
    #pragma unroll
    for (int t = 0; t < 2; t++)
      wf[j2][t] = *(const s16x8*)(w1b + (j2*16 + col)*64 + t*32 + kg*8);
  float bb[8];
  #pragma unroll
  for (int j2 = 0; j2 < 8; j2++) bb[j2] = b1[j2*16 + col];

  int wave = (int)((blockIdx.x*blockDim.x + threadIdx.x) >> 6);
  int g0 = wave, g1 = wave + 12288;
  int ma0 = g0*4 + (col >> 2), ma1 = g1*4 + (col >> 2);
  int me0 = g0*4 + kg,         me1 = g1*4 + kg;

  int e00 = elem[ma0*8 + kg], e01 = elem[ma0*8 + 4 + kg];
  int e10 = elem[ma1*8 + kg], e11 = elem[ma1*8 + 4 + kg];
  int4 p0l = *(const int4*)(pos + me0*8), p0h = *(const int4*)(pos + me0*8 + 4);
  int4 p1l = *(const int4*)(pos + me1*8), p1h = *(const int4*)(pos + me1*8 + 4);
  s16x8 a00 = *(const s16x8*)(xtb + (size_t)e00*32 + b*8);
  s16x8 a01 = *(const s16x8*)(xtb + (size_t)e01*32 + b*8);
  s16x8 a10 = *(const s16x8*)(xtb + (size_t)e10*32 + b*8);
  s16x8 a11 = *(const s16x8*)(xtb + (size_t)e11*32 + b*8);

  int pe0[8] = {p0l.x,p0l.y,p0l.z,p0l.w,p0h.x,p0h.y,p0h.z,p0h.w};
  int pe1[8] = {p1l.x,p1l.y,p1l.z,p1l.w,p1h.x,p1h.y,p1h.z,p1h.w};

  #pragma unroll
  for (int j2 = 0; j2 < 8; j2++){
    f32x4 c = {0.f,0.f,0.f,0.f};
    c = __builtin_amdgcn_mfma_f32_16x16x32_bf16(a00, wf[j2][0], c, 0, 0, 0);
    c = __builtin_amdgcn_mfma_f32_16x16x32_bf16(a01, wf[j2][1], c, 0, 0, 0);
    uint2 d; d.x = pk2(c[0]+bb[j2], c[1]+bb[j2]); d.y = pk2(c[2]+bb[j2], c[3]+bb[j2]);
    *(uint2*)(hbuf + (size_t)pe0[j2]*64 + col*4) = d;
  }
  #pragma unroll
  for (int j2 = 0; j2 < 8; j2++){
    f32x4 c = {0.f,0.f,0.f,0.f};
    c = __builtin_amdgcn_mfma_f32_16x16x32_bf16(a10, wf[j2][0], c, 0, 0, 0);
    c = __builtin_amdgcn_mfma_f32_16x16x32_bf16(a11, wf[j2][1], c, 0, 0, 0);
    uint2 d; d.x = pk2(c[0]+bb[j2], c[1]+bb[j2]); d.y = pk2(c[2]+bb[j2], c[3]+bb[j2]);
    *(uint2*)(hbuf + (size_t)pe1[j2]*64 + col*4) = d;
  }
}

// ---------- conv2: one-shot, 2 groups/wave, W2 staged in LDS (frag order) ----------
// grid MUST be 3072 blocks x 256
__global__ __launch_bounds__(256) void k_conv2(const int* __restrict__ elem,
    const u16* __restrict__ h1, const u16* __restrict__ w2b,
    const float* __restrict__ b2, const int* __restrict__ pos, u16* __restrict__ hbuf)
{
  __shared__ u16 wl[16384];   // 32 frags x 64 lanes x 8 bf16, chunk (j2*4+t)*64+lane
  #pragma unroll
  for (int r = 0; r < 8; r++){
    int q = threadIdx.x + 256*r;
    int j2t = q >> 6, ln = q & 63;
    int cc = ln & 15, kk = ln >> 4;
    int j2 = j2t >> 2, tt = j2t & 3;
    *(s16x8*)(wl + (size_t)q*8) =
        *(const s16x8*)(w2b + (j2*16 + cc)*128 + tt*32 + kk*8);
  }

  const int lane = threadIdx.x & 63;
  const int col = lane & 15, kg = lane >> 4, b = lane & 3;
  const int p = kg >> 1;            // slot parity
  const int c0 = (kg & 1)*8;        // channel offset
  float bb[8];
  #pragma unroll
  for (int j2 = 0; j2 < 8; j2++) bb[j2] = b2[j2*16 + col];

  int wave = (int)((blockIdx.x*blockDim.x + threadIdx.x) >> 6);
  int g0 = wave, g1 = wave + 12288;
  int ma0 = g0*4 + (col >> 2), ma1 = g1*4 + (col >> 2);
  int me0 = g0*4 + kg,         me1 = g1*4 + kg;

  int4 e0l = *(const int4*)(elem + ma0*8), e0h = *(const int4*)(elem + ma0*8 + 4);
  int4 e1l = *(const int4*)(elem + ma1*8), e1h = *(const int4*)(elem + ma1*8 + 4);
  int4 p0l = *(const int4*)(pos + me0*8),  p0h = *(const int4*)(pos + me0*8 + 4);
  int4 p1l = *(const int4*)(pos + me1*8),  p1h = *(const int4*)(pos + me1*8 + 4);

  int v00 = p ? e0l.y : e0l.x, v01 = p ? e0l.w : e0l.z;
  int v02 = p ? e0h.y : e0h.x, v03 = p ? e0h.w : e0h.z;
  int v10 = p ? e1l.y : e1l.x, v11 = p ? e1l.w : e1l.z;
  int v12 = p ? e1h.y : e1h.x, v13 = p ? e1h.w : e1h.z;

  s16x8 af0[4], af1[4];
  af0[0] = *(const s16x8*)(h1 + (size_t)v00*64 + b*16 + c0);
  af0[1] = *(const s16x8*)(h1 + (size_t)v01*64 + b*16 + c0);
  af0[2] = *(const s16x8*)(h1 + (size_t)v02*64 + b*16 + c0);
  af0[3] = *(const s16x8*)(h1 + (size_t)v03*64 + b*16 + c0);
  af1[0] = *(const s16x8*)(h1 + (size_t)v10*64 + b*16 + c0);
  af1[1] = *(const s16x8*)(h1 + (size_t)v11*64 + b*16 + c0);
  af1[2] = *(const s16x8*)(h1 + (size_t)v12*64 + b*16 + c0);
  af1[3] = *(const s16x8*)(h1 + (size_t)v13*64 + b*16 + c0);

  int pe0[8] = {p0l.x,p0l.y,p0l.z,p0l.w,p0h.x,p0h.y,p0h.z,p0h.w};
  int pe1[8] = {p1l.x,p1l.y,p1l.z,p1l.w,p1h.x,p1h.y,p1h.z,p1h.w};

  __syncthreads();   // W stage visible

  #pragma unroll
  for (int j2 = 0; j2 < 8; j2++){
    s16x8 w0 = *(const s16x8*)(wl + ((size_t)(j2*4 + 0)*64 + lane)*8);
    s16x8 w1 = *(const s16x8*)(wl + ((size_t)(j2*4 + 1)*64 + lane)*8);
    s16x8 w2 = *(const s16x8*)(wl + ((size_t)(j2*4 + 2)*64 + lane)*8);
    s16x8 w3 = *(const s16x8*)(wl + ((size_t)(j2*4 + 3)*64 + lane)*8);
    f32x4 c = {0.f,0.f,0.f,0.f};
    c = __builtin_amdgcn_mfma_f32_16x16x32_bf16(af0[0], w0, c, 0, 0, 0);
    c = __builtin_amdgcn_mfma_f32_16x16x32_bf16(af0[1], w1, c, 0, 0, 0);
    c = __builtin_amdgcn_mfma_f32_16x16x32_bf16(af0[2], w2, c, 0, 0, 0);
    c = __builtin_amdgcn_mfma_f32_16x16x32_bf16(af0[3], w3, c, 0, 0, 0);
    uint2 d; d.x = pk2(c[0]+bb[j2], c[1]+bb[j2]); d.y = pk2(c[2]+bb[j2], c[3]+bb[j2]);
    *(uint2*)(hbuf + (size_t)pe0[j2]*64 + col*4) = d;
  }
  #pragma unroll
  for (int j2 = 0; j2 < 8; j2++){
    s16x8 w0 = *(const s16x8*)(wl + ((size_t)(j2*4 + 0)*64 + lane)*8);
    s16x8 w1 = *(const s16x8*)(wl + ((size_t)(j2*4 + 1)*64 + lane)*8);
    s16x8 w2 = *(const s16x8*)(wl + ((size_t)(j2*4 + 2)*64 + lane)*8);
    s16x8 w3 = *(const s16x8*)(wl + ((size_t)(j2*4 + 3)*64 + lane)*8);
    f32x4 c = {0.f,0.f,0.f,0.f};
    c = __builtin_amdgcn_mfma_f32_16x16x32_bf16(af1[0], w0, c, 0, 0, 0);
    c = __builtin_amdgcn_mfma_f32_16x16x32_bf16(af1[1], w1, c, 0, 0, 0);
    c = __builtin_amdgcn_mfma_f32_16x16x32_bf16(af1[2], w2, c, 0, 0, 0);
    c = __builtin_amdgcn_mfma_f32_16x16x32_bf16(af1[3], w3, c, 0, 0, 0);
    uint2 d; d.x = pk2(c[0]+bb[j2], c[1]+bb[j2]); d.y = pk2(c[2]+bb[j2], c[3]+bb[j2]);
    *(uint2*)(hbuf + (size_t)pe1[j2]*64 + col*4) = d;
  }
}

// ---------- segmented reduce: contiguous 14-vertex chunks, half-wave per vertex ----------
// grid MUST be REDB blocks x 256. Lanes 0-31: even vertex of pair, 32-63: odd.
// Within half: k8 = chunk (col pair), rg = row-group (4 rows per load step).
__global__ __launch_bounds__(256) void k_reduce(const u16* __restrict__ hbuf,
    const int* __restrict__ rows, u16* __restrict__ mbuf, float* __restrict__ stat)
{
  int lane = threadIdx.x & 63, wid = threadIdx.x >> 6;
  int half = lane >> 5;
  int hl   = lane & 31;
  int k8   = lane & 7;
  int rg   = (lane >> 3) & 3;
  int w = (blockIdx.x*blockDim.x + threadIdx.x) >> 6;
  int v0 = w * VPW;

  int vv = v0 + lane;
  int rr = 0;
  if (lane < VPW + 1) rr = (vv < NV) ? rows[vv] : NPOS;

  int rs[7], ce[7];
  #pragma unroll
  for (int j = 0; j < 7; j++){
    rs[j] = __shfl(rr, 2*j + half);
    ce[j] = __shfl(rr, 2*j + half + 1) - rs[j];
  }

  // phase 1: issue first 2 chunk-loads for all 7 pairs (14 loads in flight)
  uint4 d0[7], d1[7];
  #pragma unroll
  for (int j = 0; j < 7; j++){
    uint4 z = {0u,0u,0u,0u};
    d0[j] = z; d1[j] = z;
    const u16* base = hbuf + (size_t)rs[j]*64 + hl*8;
    if (rg     < ce[j]) d0[j] = *(const uint4*)(base);
    if (4 + rg < ce[j]) d1[j] = *(const uint4*)(base + 4*64);
  }

  float st_s0 = 0.f, st_q0 = 0.f, st_s1 = 0.f, st_q1 = 0.f;

  // phase 2: accumulate, rare tail, 2-level fold, write means
  #pragma unroll
  for (int j = 0; j < 7; j++){
    float a0,a1,a2,a3,a4,a5,a6,a7;
    {
      uint4 dA = d0[j], dB = d1[j];
      a0 = bf2f_lo(dA.x)+bf2f_lo(dB.x); a1 = bf2f_hi(dA.x)+bf2f_hi(dB.x);
      a2 = bf2f_lo(dA.y)+bf2f_lo(dB.y); a3 = bf2f_hi(dA.y)+bf2f_hi(dB.y);
      a4 = bf2f_lo(dA.z)+bf2f_lo(dB.z); a5 = bf2f_hi(dA.z)+bf2f_hi(dB.z);
      a6 = bf2f_lo(dA.w)+bf2f_lo(dB.w); a7 = bf2f_hi(dA.w)+bf2f_hi(dB.w);
    }
    for (int p = 8; p < ce[j]; p += 4){
      uint4 d = {0u,0u,0u,0u};
      if (p + rg < ce[j]) d = *(const uint4*)(hbuf + (size_t)(rs[j]+p)*64 + hl*8);
      a0 += bf2f_lo(d.x); a1 += bf2f_hi(d.x); a2 += bf2f_lo(d.y); a3 += bf2f_hi(d.y);
      a4 += bf2f_lo(d.z); a5 += bf2f_hi(d.z); a6 += bf2f_lo(d.w); a7 += bf2f_hi(d.w);
    }
    // fold 4 row-groups within each 32-lane half: strides 8, 16
    #pragma unroll
    for (int off = 8; off <= 16; off <<= 1){
      a0 += __shfl_xor(a0, off); a1 += __shfl_xor(a1, off);
      a2 += __shfl_xor(a2, off); a3 += __shfl_xor(a3, off);
      a4 += __shfl_xor(a4, off); a5 += __shfl_xor(a5, off);
      a6 += __shfl_xor(a6, off); a7 += __shfl_xor(a7, off);
    }
    int v = v0 + 2*j + half;
    if (hl < 8 && v < NV){
      float inv = 1.0f / fmaxf((float)ce[j], 1.0f);
      float c0b[4] = {a0*inv, a1*inv, a2*inv, a3*inv};   // col 2k8, batches 0..3
      float c1b[4] = {a4*inv, a5*inv, a6*inv, a7*inv};   // col 2k8+1
      #pragma unroll
      for (int q = 0; q < 4; q++){
        *(u32*)(mbuf + (size_t)v*64 + q*16 + 2*k8) = pk2(c0b[q], c1b[q]);
        st_s0 += c0b[q]; st_q0 += c0b[q]*c0b[q];
        st_s1 += c1b[q]; st_q1 += c1b[q]*c1b[q];
      }
    }
  }

  // combine halves, then block reduce
  st_s0 += __shfl_xor(st_s0, 32); st_q0 += __shfl_xor(st_q0, 32);
  st_s1 += __shfl_xor(st_s1, 32); st_q1 += __shfl_xor(st_q1, 32);
  __shared__ float ls[4][16], lq[4][16];
  if (lane < 8){
    ls[wid][2*k8] = st_s0; ls[wid][2*k8+1] = st_s1;
    lq[wid][2*k8] = st_q0; lq[wid][2*k8+1] = st_q1;
  }
  __syncthreads();
  if (threadIdx.x < 32){
    int c2 = threadIdx.x & 15, which = threadIdx.x >> 4;
    float tot = 0.f;
    #pragma unroll
    for (int w2 = 0; w2 < 4; w2++) tot += which ? lq[w2][c2] : ls[w2][c2];
    unsafeAtomicAdd(stat + which*16 + c2, tot);
  }
}

// ---------- apply BN1 (inline finalize) + relu: mbuf bf16 -> h1[v][b][16] bf16 ----------
__global__ __launch_bounds__(256) void k_apply1(const u16* __restrict__ mbuf,
    const float* __restrict__ stat, const float* __restrict__ gamma,
    const float* __restrict__ beta, u16* __restrict__ h1)
{
  __shared__ float sc[16], sh[16];
  if (threadIdx.x < 16){
    int co = threadIdx.x;
    const float invn = 1.0f / (float)(NB*NV);
    float m = stat[co]*invn;
    float var = stat[16+co]*invn - m*m;
    float s = gamma[co]*rsqrtf(var + 1e-5f);
    sc[co] = s; sh[co] = beta[co] - m*s;
  }
  __syncthreads();
  int idx = blockIdx.x*256 + threadIdx.x;
  int v = idx >> 2, b = idx & 3;
  if (v >= NV) return;
  const uint4* src = (const uint4*)(mbuf + (size_t)v*64 + b*16);
  uint4 m0 = src[0], m1 = src[1];
  u32 mw[8] = {m0.x,m0.y,m0.z,m0.w,m1.x,m1.y,m1.z,m1.w};
  u16 o[16] __attribute__((aligned(16)));
  #pragma unroll
  for (int k = 0; k < 8; k++){
    int c0 = 2*k, c1 = 2*k + 1;
    float va = bf2f_lo(mw[k])*sc[c0] + sh[c0];
    float vb = bf2f_hi(mw[k])*sc[c1] + sh[c1];
    o[c0] = f2bf(fmaxf(va, 0.f));
    o[c1] = f2bf(fmaxf(vb, 0.f));
  }
  uint4* dst = (uint4*)(h1 + (size_t)v*64 + b*16);
  dst[0] = *(uint4*)(o);
  dst[1] = *(uint4*)(o + 8);
}

// ---------- final: BN2 (inline finalize) + skip GEMV + relu + transpose ----------
__global__ __launch_bounds__(256) void k_final(const u16* __restrict__ mbuf,
    const float* __restrict__ stat, const float* __restrict__ gamma,
    const float* __restrict__ beta, const float* __restrict__ x,
    const float* __restrict__ wsk, const float* __restrict__ bsk, float* __restrict__ out)
{
  __shared__ float sc[16], sh[16];
  if (threadIdx.x < 16){
    int co = threadIdx.x;
    const float invn = 1.0f / (float)(NB*NV);
    float m = stat[co]*invn;
    float var = stat[16+co]*invn - m*m;
    float s = gamma[co]*rsqrtf(var + 1e-5f);
    sc[co] = s; sh[co] = beta[co] - m*s + bsk[co];
  }
  __syncthreads();
  int n = blockIdx.x*blockDim.x + threadIdx.x;
  int b = blockIdx.y;
  if (n >= NV) return;
  float xv[8];
  #pragma unroll
  for (int c = 0; c < 8; c++) xv[c] = x[((size_t)b*8 + c)*NV + n];
  const uint4* src = (const uint4*)(mbuf + (size_t)n*64 + b*16);
  uint4 m0 = src[0], m1 = src[1];
  u32 mw[8] = {m0.x,m0.y,m0.z,m0.w,m1.x,m1.y,m1.z,m1.w};
  #pragma unroll
  for (int k = 0; k < 8; k++){
    #pragma unroll
    for (int h = 0; h < 2; h++){
      int co = 2*k + h;
      float val = (h ? bf2f_hi(mw[k]) : bf2f_lo(mw[k]))*sc[co] + sh[co];
      #pragma unroll
      for (int c = 0; c < 8; c++) val += wsk[co*8+c]*xv[c];
      out[((size_t)b*16 + co)*NV + n] = fmaxf(val, 0.f);
    }
  }
}

extern "C" void kernel_launch(void* const* d_in, const int* in_sizes, int n_in,
                              void* d_out, int out_size, void* d_ws, size_t ws_size,
                              hipStream_t stream) {
  const float* x    = (const float*)d_in[0];
  const int*   elem = (const int*)  d_in[1];
  const float* W1   = (const float*)d_in[2];
  const float* b1   = (const float*)d_in[3];
  const float* g1   = (const float*)d_in[4];
  const float* be1  = (const float*)d_in[5];
  const float* W2   = (const float*)d_in[6];
  const float* b2   = (const float*)d_in[7];
  const float* g2   = (const float*)d_in[8];
  const float* be2  = (const float*)d_in[9];
  const float* Wsk  = (const float*)d_in[10];
  const float* bsk  = (const float*)d_in[11];
  float* out = (float*)d_out;

  if (ws_size < (size_t)WS_NEED) return;  // visible failure rather than corruption

  char* ws = (char*)d_ws;
  int*   cnt  = (int*)  (ws + OFF_CNT);
  int*   next = (int*)  (ws + OFF_NEXT);
  float* stat = (float*)(ws + OFF_STAT);   // [0..31] BN1, [32..63] BN2
  int*   rows = (int*)  (ws + OFF_ROWS);
  int*   bsum = (int*)  (ws + OFF_BSUM);
  int*   pos  = (int*)  (ws + OFF_POS);
  u16*   xtb  = (u16*)  (ws + OFF_XTB);
  u16*   w1b  = (u16*)  (ws + OFF_W1B);
  u16*   w2b  = (u16*)  (ws + OFF_W2B);
  u16*   h1   = (u16*)  (ws + OFF_H1);
  u16*   mbuf = (u16*)  (ws + OFF_MBUF);
  u16*   hbuf = (u16*)  (ws + OFF_HBUF);

  // zero cnt + next + stat (contiguous, ~0.8 MB)
  hipMemsetAsync(ws, 0, OFF_STAT + 384, stream);

  k_prep<<<NBLK + 1024, 256, 0, stream>>>(elem, x, W1, W2, cnt, xtb, w1b, w2b);
  k_scan_a<<<NBLK, 256, 0, stream>>>(cnt, bsum);
  k_scan_c<<<NBLK, 256, 0, stream>>>(cnt, bsum, rows);
  k_pos<<<NPOS/256, 256, 0, stream>>>(elem, rows, next, pos);

  k_conv1<<<3072, 256, 0, stream>>>(elem, xtb, w1b, b1, pos, hbuf);
  k_reduce<<<REDB, 256, 0, stream>>>(hbuf, rows, mbuf, stat);
  k_apply1<<<(NV*4 + 255)/256, 256, 0, stream>>>(mbuf, stat, g1, be1, h1);

  k_conv2<<<3072, 256, 0, stream>>>(elem, h1, w2b, b2, pos, hbuf);
  k_reduce<<<REDB, 256, 0, stream>>>(hbuf, rows, mbuf, stat + 32);
  k_final<<<dim3((NV+255)/256, NB), 256, 0, stream>>>(mbuf, stat + 32, g2, be2, x, Wsk, bsk, out);
}